// Round 13
// baseline (1499.862 us; speedup 1.0000x reference)
//
#include <hip/hip_runtime.h>
#include <hip/hip_bf16.h>
#include <cstdint>
#include <cstddef>
#include <type_traits>

// ---- problem constants ----
#define NN     20000
#define FIN_D  64
#define H_D    128
#define M_D    16
#define EIA_D  256000
#define EIR_D  256000
#define EIT_D  100000
#define EIN_D  257
#define EHID_D 514
#define NIN_D  144
#define NHID_D 256
#define APAD   544          // padded EHID; 17 k-tiles of 32
#define BUPAD  272          // APAD/2 uints per bf16 row (A and B tables)

typedef short bfrag __attribute__((ext_vector_type(8)));   // 8 bf16 (4 VGPRs)
typedef float ffrag __attribute__((ext_vector_type(4)));   // 4 fp32 acc

__device__ __forceinline__ float siluf(float x) {
    return x * __builtin_amdgcn_rcpf(1.f + __expf(-x));
}
__device__ __forceinline__ float reluf(float x) { return x > 0.f ? x : 0.f; }
__device__ __forceinline__ unsigned short f2bf(float f) {  // RNE fp32->bf16
    unsigned u = __float_as_uint(f);
    return (unsigned short)((u + 0x7FFFu + ((u >> 16) & 1u)) >> 16);
}
__device__ __forceinline__ float bf2f(unsigned short h) { return __uint_as_float(((unsigned)h) << 16); }
__device__ __forceinline__ float bf_lo(unsigned u) { return __uint_as_float(u << 16); }
__device__ __forceinline__ float bf_hi(unsigned u) { return __uint_as_float(u & 0xFFFF0000u); }
__device__ __forceinline__ unsigned pkbf(float f0, float f1) {
    __hip_bfloat162 h = __float22bfloat162_rn(make_float2(f0, f1));
    return *(unsigned*)&h;
}

// ---------------- CSR build ----------------
__global__ void k_filli(int* p, int v, int n) {
    int i = blockIdx.x * 256 + threadIdx.x; if (i < n) p[i] = v;
}
__global__ void k_iota(int* p, int n) {
    int i = blockIdx.x * 256 + threadIdx.x; if (i < n) p[i] = i;
}
__global__ void k_hist(const int* __restrict__ si, int nE, int* __restrict__ cnt) {
    int e = blockIdx.x * 256 + threadIdx.x; if (e < nE) atomicAdd(&cnt[si[e]], 1);
}
__global__ void k_scan4(const int* __restrict__ cnt4, int n, int* __restrict__ rp4) {
    const int* cnt = cnt4 + (size_t)blockIdx.x * n;
    int* rp = rp4 + (size_t)blockIdx.x * (n + 1);
    __shared__ int tmp[256];
    __shared__ int carry;
    if (threadIdx.x == 0) { carry = 0; rp[0] = 0; }
    __syncthreads();
    for (int base = 0; base < n; base += 256) {
        int i = base + threadIdx.x;
        int v = (i < n) ? cnt[i] : 0;
        tmp[threadIdx.x] = v;
        __syncthreads();
        for (int off = 1; off < 256; off <<= 1) {
            int t = (threadIdx.x >= off) ? tmp[threadIdx.x - off] : 0;
            __syncthreads();
            tmp[threadIdx.x] += t;
            __syncthreads();
        }
        if (i < n) rp[i + 1] = carry + tmp[threadIdx.x];
        __syncthreads();
        if (threadIdx.x == 0) carry += tmp[255];
        __syncthreads();
    }
}
__global__ void k_scatter(const int* __restrict__ sj, const int* __restrict__ si, int nE,
                          const int* __restrict__ rp, int* __restrict__ cursor,
                          int* __restrict__ colj, int* __restrict__ dsti) {
    int e = blockIdx.x * 256 + threadIdx.x;
    if (e >= nE) return;
    int i = si[e];
    int p = rp[i] + atomicAdd(&cursor[i], 1);
    colj[p] = sj[e];
    if (dsti) dsti[p] = i;
}

// ---------------- weight prep: transpose + hi/lo bf16 split ----------------
struct PrepDesc { const float* src; unsigned dstOff; int K, N, Kpad, Npad; };
struct PrepArgs { PrepDesc d[29]; };
__global__ void k_prep(PrepArgs pa, unsigned short* __restrict__ Wt) {
    PrepDesc de = pa.d[blockIdx.x];
    int tot = de.Npad * de.Kpad;
    unsigned short* hi = Wt + de.dstOff;
    unsigned short* lo = hi + tot;
    for (int i = blockIdx.y * 256 + threadIdx.x; i < tot; i += gridDim.y * 256) {
        int n = i / de.Kpad, k = i - n * de.Kpad;
        float v = (n < de.N && k < de.K) ? de.src[(size_t)k * de.N + n] : 0.f;
        unsigned short h = f2bf(v);
        hi[i] = h;
        lo[i] = f2bf(v - bf2f(h));
    }
}

// ew2 [514][16] -> MFMA B-frag order (zero beyond k>=514); cw1 [16][64] -> gate B-frags
__global__ void k_prep_ew2(const float* __restrict__ eg_e_w2, const float* __restrict__ eg_c_w1,
                           unsigned short* __restrict__ Wf) {
    int pidx = blockIdx.x;
    const float* src = eg_e_w2 + (size_t)pidx * EHID_D * M_D;
    unsigned short* hi = Wf + (size_t)pidx * 8704;
    unsigned short* lo = Wf + 4 * 8704 + (size_t)pidx * 8704;
    for (int idx = threadIdx.x; idx < 8704; idx += 256) {
        int t = idx >> 9, rem = idx & 511;
        int lane = rem >> 3, j2 = rem & 7;
        int k = t * 32 + ((lane >> 4) << 3) + j2;
        int n = lane & 15;
        float v = (k < EHID_D) ? src[(size_t)k * 16 + n] : 0.f;
        unsigned short h = f2bf(v);
        hi[idx] = h;
        lo[idx] = f2bf(v - bf2f(h));
    }
    const float* cw1 = eg_c_w1 + (size_t)pidx * 16 * 64;
    unsigned short* ghi = Wf + 69632 + (size_t)pidx * 4096;
    unsigned short* glo = ghi + 2048;
    for (int idx = threadIdx.x; idx < 2048; idx += 256) {
        int nt = idx >> 9, rem = idx & 511;
        int lane = rem >> 3, j = rem & 7;
        int q = lane >> 4, mm = lane & 15;
        int k = q * 8 + j;
        float v = (k < 16) ? cw1[(size_t)k * 64 + nt * 16 + mm] : 0.f;
        unsigned short h = f2bf(v);
        ghi[idx] = h;
        glo[idx] = f2bf(v - bf2f(h));
    }
}

struct MMJob {
    const float* A; const float* A2;
    const int* gi0; const int* gi1;
    const unsigned short* Wh; const unsigned short* Wl;
    const float* bias; const float* res;
    float* C; unsigned short* C2;
    const float* da; const float* db;
    float* dota; float* dotb;
};
struct MMJobs { MMJob j[4]; };

// ---------------- full-K resident MFMA GEMM (K = KT*32 <= 256) ----------------
// A staged once in LDS (bf16), bn tiles looped internally. DOT: direct-store per-row dots.
// GATHER: row = [A[gi0]](128) | A2[gi1](stride s2)] split at k=128; strips beyond Kact zeroed
// (zero-weight pad protection: OOB gather bytes could be NaN-pattern — round-9 lesson).
// RES: += res in epilogue. OBF pad cols Nc..ldc-1 zeroed.
template<int ACT, bool OBF, int DOT, bool NOC, int KT, bool GATHER, bool RES>
__global__ __launch_bounds__(256) void k_mmf(MMJobs js, int M, int Nc, int ldc, int nbn,
                                             int Kact, int s2) {
    constexpr int K = KT * 32;
    __shared__ __align__(16) unsigned short sAh[128 * K];
    const MMJob jb = js.j[blockIdx.z];
    const int tid = threadIdx.x;
    const int bm = blockIdx.x * 128;
    const int wv = tid >> 6, lane = tid & 63;
    const int q = lane >> 4, mm = lane & 15;
    const int sr = tid >> 1;
    const int sks = (tid & 1) * 16;
    const int gm_s = bm + sr;
    const int sgmt = sr >> 4, smm = sr & 15, qb = (tid & 1) * 2;
    int gidx0 = 0, gidx1 = 0;
    if (GATHER && gm_s < M) { gidx0 = jb.gi0[gm_s]; gidx1 = jb.gi1[gm_s]; }
#pragma unroll
    for (int t = 0; t < KT; ++t) {
        float v[16];
        int kk = t * 32 + sks;
        bool valid = (gm_s < M) && (kk < Kact);
        if (valid) {
            const float* src;
            if (GATHER) src = (kk < 128) ? (jb.A + (size_t)gidx0 * 128 + kk)
                                         : (jb.A2 + (size_t)gidx1 * s2 + (kk - 128));
            else src = jb.A + (size_t)gm_s * K + kk;
#pragma unroll
            for (int i = 0; i < 4; ++i) {
                float4 t4 = ((const float4*)src)[i];
                v[4 * i] = t4.x; v[4 * i + 1] = t4.y; v[4 * i + 2] = t4.z; v[4 * i + 3] = t4.w;
            }
        } else {
#pragma unroll
            for (int i = 0; i < 16; ++i) v[i] = 0.f;
        }
#pragma unroll
        for (int o = 0; o < 2; ++o) {
            unsigned hw[4];
#pragma unroll
            for (int p = 0; p < 4; ++p)
                hw[p] = pkbf(v[o * 8 + 2 * p], v[o * 8 + 2 * p + 1]);
            int off16 = ((sgmt * KT + t) * 4 + qb + o) * 16 + smm;
            ((uint4*)sAh)[off16] = make_uint4(hw[0], hw[1], hw[2], hw[3]);
        }
    }
    __syncthreads();
    float dra[2][4] = {}, drb[2][4] = {};
    for (int b = 0; b < nbn; ++b) {
        const int bn = b * 64;
        ffrag acc[2][4];
#pragma unroll
        for (int mt = 0; mt < 2; ++mt)
#pragma unroll
            for (int nt = 0; nt < 4; ++nt)
#pragma unroll
                for (int r = 0; r < 4; ++r) acc[mt][nt][r] = 0.f;
#pragma unroll
        for (int t = 0; t < KT; ++t) {
            bfrag bh[4], bl[4];
#pragma unroll
            for (int nt = 0; nt < 4; ++nt) {
                size_t woff = (size_t)(bn + nt * 16 + mm) * K + t * 32 + q * 8;
                bh[nt] = *(const bfrag*)(jb.Wh + woff);
                bl[nt] = *(const bfrag*)(jb.Wl + woff);
            }
#pragma unroll
            for (int mt = 0; mt < 2; ++mt) {
                int off16 = (((wv * 2 + mt) * KT + t) * 4 + q) * 16 + mm;
                bfrag ah = ((const bfrag*)sAh)[off16];
#pragma unroll
                for (int nt = 0; nt < 4; ++nt) {
                    acc[mt][nt] = __builtin_amdgcn_mfma_f32_16x16x32_bf16(ah, bh[nt], acc[mt][nt], 0, 0, 0);
                    acc[mt][nt] = __builtin_amdgcn_mfma_f32_16x16x32_bf16(ah, bl[nt], acc[mt][nt], 0, 0, 0);
                }
            }
        }
        if (DOT >= 1) {
            float dav[4], dbv[4];
#pragma unroll
            for (int nt = 0; nt < 4; ++nt) {
                int gn = bn + nt * 16 + mm;
                dav[nt] = (gn < Nc) ? jb.da[gn] : 0.f;
                if (DOT == 2) dbv[nt] = (gn < Nc) ? jb.db[gn] : 0.f;
            }
#pragma unroll
            for (int mt = 0; mt < 2; ++mt)
#pragma unroll
                for (int r = 0; r < 4; ++r)
#pragma unroll
                    for (int nt = 0; nt < 4; ++nt) {
                        dra[mt][r] += acc[mt][nt][r] * dav[nt];
                        if (DOT == 2) drb[mt][r] += acc[mt][nt][r] * dbv[nt];
                    }
        }
        const bool doC2 = jb.C2 != nullptr;
        if (!NOC || doC2) {
#pragma unroll
            for (int mt = 0; mt < 2; ++mt) {
#pragma unroll
                for (int nt = 0; nt < 4; ++nt) {
                    int gn = bn + nt * 16 + mm;
                    bool inb = gn < Nc;
                    bool padz = OBF && !NOC && !inb && gn < ldc;
                    if (!inb && !padz) continue;
#pragma unroll
                    for (int r = 0; r < 4; ++r) {
                        int gm = bm + wv * 32 + mt * 16 + q * 4 + r;
                        if (gm >= M) continue;
                        if (padz) {
                            ((unsigned short*)jb.C)[(size_t)gm * ldc + gn] = 0;
                            continue;
                        }
                        float vv = acc[mt][nt][r];
                        if (jb.bias) vv += jb.bias[gn];
                        if (ACT == 1) vv = reluf(vv);
                        if (ACT == 2) vv = siluf(vv);
                        if (RES) vv += jb.res[(size_t)gm * Nc + gn];
                        if (!NOC) {
                            if (OBF) ((unsigned short*)jb.C)[(size_t)gm * ldc + gn] = f2bf(vv);
                            else jb.C[(size_t)gm * ldc + gn] = vv;
                        }
                        if (doC2) jb.C2[(size_t)gm * ldc + gn] = f2bf(vv);
                    }
                }
            }
        }
    }
    if (DOT >= 1) {
#pragma unroll
        for (int mt = 0; mt < 2; ++mt)
#pragma unroll
            for (int r = 0; r < 4; ++r) {
                float sa = dra[mt][r];
                sa += __shfl_xor(sa, 1); sa += __shfl_xor(sa, 2);
                sa += __shfl_xor(sa, 4); sa += __shfl_xor(sa, 8);
                float sb = 0.f;
                if (DOT == 2) {
                    sb = drb[mt][r];
                    sb += __shfl_xor(sb, 1); sb += __shfl_xor(sb, 2);
                    sb += __shfl_xor(sb, 4); sb += __shfl_xor(sb, 8);
                }
                int gm = bm + wv * 32 + mt * 16 + q * 4 + r;
                if (mm == 0 && gm < M) {
                    jb.dota[gm] = sa;
                    if (DOT == 2) jb.dotb[gm] = sb;
                }
            }
    }
}

__global__ void k_nodescore(const float* __restrict__ x, const float* __restrict__ wv,
                            const float* __restrict__ b, float* __restrict__ o, int n) {
    int w = blockIdx.x * 4 + (threadIdx.x >> 6);
    int lane = threadIdx.x & 63;
    if (w >= n) return;
    const float* r = x + (size_t)w * H_D;
    float s = r[lane] * wv[lane] + r[lane + 64] * wv[lane + 64];
#pragma unroll
    for (int off = 32; off; off >>= 1) s += __shfl_xor(s, off);
    if (lane == 0) o[w] = s + b[0];
}

// ---------------- fused GAT softmax-aggregate: both graphs per launch, 4-edge unroll --------
struct GatJob {
    const int* rp; const int* cj; int hasSelf;
    const float* es; const float* ed;
    const unsigned* h16; const float* bias; float* out;
};
__global__ __launch_bounds__(256) void k_gat2(GatJob j0, GatJob j1, int N) {
    const GatJob jb = blockIdx.y ? j1 : j0;
    int node = blockIdx.x * 4 + (threadIdx.x >> 6);
    int lane = threadIdx.x & 63;
    if (node >= N) return;
    int start = jb.rp[node], end = jb.rp[node + 1];
    float edi = jb.ed[node];
    float den = 0.f, a0 = 0.f, a1 = 0.f;
    int p = start;
    for (; p + 4 <= end; p += 4) {
        int j[4]; float e[4]; unsigned u[4];
#pragma unroll
        for (int x = 0; x < 4; ++x) j[x] = jb.cj[p + x];
#pragma unroll
        for (int x = 0; x < 4; ++x) { e[x] = jb.es[j[x]]; u[x] = jb.h16[(size_t)j[x] * 64 + lane]; }
#pragma unroll
        for (int x = 0; x < 4; ++x) {
            float v = e[x] + edi;
            v = v < 0.f ? 0.2f * v : v;
            float ex = __expf(v);
            den += ex;
            a0 += ex * bf_lo(u[x]);
            a1 += ex * bf_hi(u[x]);
        }
    }
    for (; p < end; ++p) {
        int j = jb.cj[p];
        float v = jb.es[j] + edi;
        v = v < 0.f ? 0.2f * v : v;
        float ex = __expf(v);
        den += ex;
        unsigned u = jb.h16[(size_t)j * 64 + lane];
        a0 += ex * bf_lo(u);
        a1 += ex * bf_hi(u);
    }
    if (jb.hasSelf) {
        float v = jb.es[node] + edi;
        v = v < 0.f ? 0.2f * v : v;
        float ex = __expf(v);
        den += ex;
        unsigned u = jb.h16[(size_t)node * 64 + lane];
        a0 += ex * bf_lo(u);
        a1 += ex * bf_hi(u);
    }
    float inv = 1.f / (den + 1e-16f);
    float2 o;
    o.x = reluf(a0 * inv + jb.bias[2 * lane]);
    o.y = reluf(a1 * inv + jb.bias[2 * lane + 1]);
    ((float2*)(jb.out + (size_t)node * H_D))[lane] = o;
}

// ---------------- EGNN edge kernel: both graphs per launch; MFMA gate ----------------
struct EJob {
    const int* dsti; const int* cj;
    const unsigned* A16; const unsigned* Bp; const float* coors;
    const float* w_rd;
    const unsigned short* Wfh; const unsigned short* Wfl;
    const unsigned short* Wgh; const unsigned short* Wgl;
    const float* eb2; const float* cb1;
    const float* cw2; const float* cb2;
    unsigned short* me16; float* cvec;
};
__global__ __launch_bounds__(256) void k_edge2(EJob e0, EJob e1, int nE) {
    const EJob jb = blockIdx.y ? e1 : e0;
    __shared__ __align__(16) float s_w[APAD];
    __shared__ float s_cb1[64], s_cw2[64], s_eb2[16];
    __shared__ __align__(16) float sM[4][16][20];
    for (int i = threadIdx.x; i < APAD; i += 256)
        s_w[i] = (i < EHID_D) ? jb.w_rd[i] : 0.f;
    if (threadIdx.x < 64) { s_cb1[threadIdx.x] = jb.cb1[threadIdx.x]; s_cw2[threadIdx.x] = jb.cw2[threadIdx.x]; }
    if (threadIdx.x < 16) s_eb2[threadIdx.x] = jb.eb2[threadIdx.x];
    __syncthreads();
    const float cb2v = jb.cb2[0];
    const int wv = threadIdx.x >> 6, lane = threadIdx.x & 63;
    const int q = lane >> 4, mm = lane & 15;
    const int ebase = blockIdx.x * 64 + wv * 16;
    const int e = ebase + mm;
    const bool ev = e < nE;
    int ii = ev ? jb.dsti[e] : 0;
    int jj = ev ? jb.cj[e] : 0;
    float dx = jb.coors[(size_t)jj * 3]     - jb.coors[(size_t)ii * 3];
    float dy = jb.coors[(size_t)jj * 3 + 1] - jb.coors[(size_t)ii * 3 + 1];
    float dz = jb.coors[(size_t)jj * 3 + 2] - jb.coors[(size_t)ii * 3 + 2];
    float rd = dx * dx + dy * dy + dz * dz;
    const unsigned* Ar = jb.A16 + (size_t)ii * BUPAD;
    const unsigned* Br = jb.Bp + (size_t)jj * BUPAD;
    ffrag acc = {0.f, 0.f, 0.f, 0.f};
#pragma unroll 4
    for (int t = 0; t < 17; ++t) {
        int ks = t * 32 + q * 8;
        int ku = ks >> 1;
        uint4 au = *(const uint4*)(Ar + ku);
        uint4 bu = *(const uint4*)(Br + ku);
        float4 w0 = *(const float4*)(s_w + ks);
        float4 w1 = *(const float4*)(s_w + ks + 4);
        float g[8];
        g[0] = siluf(bf_lo(au.x) + bf_lo(bu.x) + rd * w0.x);
        g[1] = siluf(bf_hi(au.x) + bf_hi(bu.x) + rd * w0.y);
        g[2] = siluf(bf_lo(au.y) + bf_lo(bu.y) + rd * w0.z);
        g[3] = siluf(bf_hi(au.y) + bf_hi(bu.y) + rd * w0.w);
        g[4] = siluf(bf_lo(au.z) + bf_lo(bu.z) + rd * w1.x);
        g[5] = siluf(bf_hi(au.z) + bf_hi(bu.z) + rd * w1.y);
        g[6] = siluf(bf_lo(au.w) + bf_lo(bu.w) + rd * w1.z);
        g[7] = siluf(bf_hi(au.w) + bf_hi(bu.w) + rd * w1.w);
        bfrag ah;
        unsigned* ahp = (unsigned*)&ah;
        ahp[0] = pkbf(g[0], g[1]);
        ahp[1] = pkbf(g[2], g[3]);
        ahp[2] = pkbf(g[4], g[5]);
        ahp[3] = pkbf(g[6], g[7]);
        bfrag bh = *(const bfrag*)(jb.Wfh + (size_t)(t * 64 + lane) * 8);
        bfrag bl = *(const bfrag*)(jb.Wfl + (size_t)(t * 64 + lane) * 8);
        acc = __builtin_amdgcn_mfma_f32_16x16x32_bf16(ah, bh, acc, 0, 0, 0);
        acc = __builtin_amdgcn_mfma_f32_16x16x32_bf16(ah, bl, acc, 0, 0, 0);
    }
#pragma unroll
    for (int r = 0; r < 4; ++r) {
        int erow = q * 4 + r;
        float me = siluf(acc[r] + s_eb2[mm]);
        sM[wv][erow][mm] = me;
        int e2 = ebase + erow;
        if (e2 < nE) jb.me16[(size_t)e2 * 16 + mm] = f2bf(me);
    }
    // coordinate gate via MFMA: [16 edges] x [64 hid], k=16 channels (padded 32)
    bfrag ag;
    unsigned* agp = (unsigned*)&ag;
    if (q < 2) {
        float4 m0 = *(const float4*)&sM[wv][mm][q * 8];
        float4 m1 = *(const float4*)&sM[wv][mm][q * 8 + 4];
        agp[0] = pkbf(m0.x, m0.y);
        agp[1] = pkbf(m0.z, m0.w);
        agp[2] = pkbf(m1.x, m1.y);
        agp[3] = pkbf(m1.z, m1.w);
    } else {
        agp[0] = agp[1] = agp[2] = agp[3] = 0u;
    }
    float part[4] = {0.f, 0.f, 0.f, 0.f};
#pragma unroll
    for (int nt = 0; nt < 4; ++nt) {
        bfrag gh = *(const bfrag*)(jb.Wgh + (size_t)(nt * 64 + lane) * 8);
        bfrag gl = *(const bfrag*)(jb.Wgl + (size_t)(nt * 64 + lane) * 8);
        ffrag a2 = {0.f, 0.f, 0.f, 0.f};
        a2 = __builtin_amdgcn_mfma_f32_16x16x32_bf16(ag, gh, a2, 0, 0, 0);
        a2 = __builtin_amdgcn_mfma_f32_16x16x32_bf16(ag, gl, a2, 0, 0, 0);
        int n = nt * 16 + mm;
        float c1 = s_cb1[n], c2 = s_cw2[n];
#pragma unroll
        for (int r = 0; r < 4; ++r) part[r] += siluf(a2[r] + c1) * c2;
    }
#pragma unroll
    for (int r = 0; r < 4; ++r) {
        part[r] += __shfl_xor(part[r], 1);
        part[r] += __shfl_xor(part[r], 2);
        part[r] += __shfl_xor(part[r], 4);
        part[r] += __shfl_xor(part[r], 8);
    }
    int srcl = (lane >> 2) << 4;
    float cand0 = __shfl(part[0], srcl);
    float cand1 = __shfl(part[1], srcl);
    float cand2 = __shfl(part[2], srcl);
    float cand3 = __shfl(part[3], srcl);
    if (lane < 16) {
        int rr = lane & 3;
        float cwv = (rr == 0 ? cand0 : rr == 1 ? cand1 : rr == 2 ? cand2 : cand3) + cb2v;
        int e3 = ebase + lane;
        if (e3 < nE) {
            jb.cvec[(size_t)e3 * 3]     = cwv * dx;
            jb.cvec[(size_t)e3 * 3 + 1] = cwv * dy;
            jb.cvec[(size_t)e3 * 3 + 2] = cwv * dz;
        }
    }
}

// ---------------- EGNN CSR segment-sum: both graphs per launch ----------------
struct SJob {
    const int* rp; const unsigned short* me16; const float* cvec;
    const float* coors; float* coorsOut; float* macc;
};
__global__ __launch_bounds__(256) void k_seg2(SJob s0, SJob s1, int N) {
    const SJob jb = blockIdx.y ? s1 : s0;
    int node = blockIdx.x * 4 + (threadIdx.x >> 6);
    int lane = threadIdx.x & 63;
    if (node >= N) return;
    int s = jb.rp[node], en = jb.rp[node + 1];
    int x = lane >> 4, c = lane & 15;
    float msum = 0.f, csum = 0.f;
    for (int p = s + x; p < en; p += 4) {
        msum += bf2f(jb.me16[(size_t)p * 16 + c]);
        if (c < 3) csum += jb.cvec[(size_t)p * 3 + c];
    }
    msum += __shfl_xor(msum, 16); msum += __shfl_xor(msum, 32);
    csum += __shfl_xor(csum, 16); csum += __shfl_xor(csum, 32);
    if (lane < 16) jb.macc[(size_t)node * M_D + lane] = msum;
    if (lane < 3) jb.coorsOut[(size_t)node * 3 + lane] = jb.coors[(size_t)node * 3 + lane] + csum;
}

__global__ void k_dist(const float* __restrict__ Hb, const float* __restrict__ w2,
                       const float* __restrict__ b2, float* __restrict__ dist, int nE) {
    int e = blockIdx.x * 4 + (threadIdx.x >> 6);
    int lane = threadIdx.x & 63;
    if (e >= nE) return;
    const float* r = Hb + (size_t)e * H_D;
    float s = r[lane] * w2[lane] + r[lane + 64] * w2[lane + 64];
#pragma unroll
    for (int off = 32; off; off >>= 1) s += __shfl_xor(s, off);
    if (lane == 0) dist[e] = reluf(s + b2[0]);
}

// ---------------- host ----------------
extern "C" void kernel_launch(void* const* d_in, const int* in_sizes, int n_in,
                              void* d_out, int out_size, void* d_ws, size_t ws_size,
                              hipStream_t stream) {
    const float* x1_in = (const float*)d_in[0];
    const float* x2_in = (const float*)d_in[1];
    const float* pos1  = (const float*)d_in[2];
    const float* pos2  = (const float*)d_in[3];
    const int* ei_intra1 = (const int*)d_in[4];
    const int* ei_intra2 = (const int*)d_in[5];
    const int* ei_12 = (const int*)d_in[6];
    const int* ei_21 = (const int*)d_in[7];
    const int* ei_int = (const int*)d_in[8];
    const float* g0_w  = (const float*)d_in[9];
    const float* g0_as = (const float*)d_in[10];
    const float* g0_ad = (const float*)d_in[11];
    const float* g0_b  = (const float*)d_in[12];
    const float* g1_w  = (const float*)d_in[13];
    const float* g1_as = (const float*)d_in[14];
    const float* g1_ad = (const float*)d_in[15];
    const float* g1_b  = (const float*)d_in[16];
    const float* it_ws = (const float*)d_in[17];
    const float* it_wd = (const float*)d_in[18];
    const float* it_as = (const float*)d_in[19];
    const float* it_ad = (const float*)d_in[20];
    const float* it_b  = (const float*)d_in[21];
    const float* eg_e_w1 = (const float*)d_in[22];
    const float* eg_e_b1 = (const float*)d_in[23];
    const float* eg_e_w2 = (const float*)d_in[24];
    const float* eg_e_b2 = (const float*)d_in[25];
    const float* eg_c_w1 = (const float*)d_in[26];
    const float* eg_c_b1 = (const float*)d_in[27];
    const float* eg_c_w2 = (const float*)d_in[28];
    const float* eg_c_b2 = (const float*)d_in[29];
    const float* eg_n_w1 = (const float*)d_in[30];
    const float* eg_n_b1 = (const float*)d_in[31];
    const float* eg_n_w2 = (const float*)d_in[32];
    const float* eg_n_b2 = (const float*)d_in[33];
    const float* lin_w = (const float*)d_in[34];
    const float* lin_b = (const float*)d_in[35];
    const float* aux_w1 = (const float*)d_in[36];
    const float* aux_b1 = (const float*)d_in[37];
    const float* aux_w2 = (const float*)d_in[38];
    const float* aux_b2 = (const float*)d_in[39];
    float* dout = (float*)d_out;

    // ---- workspace layout ----
    float* wsf = (float*)d_ws;
    size_t off = 0;
    auto alloc = [&](size_t nfl) { float* p = wsf + off; off += (nfl + 255) & ~(size_t)255; return p; };
    float* x1a = alloc((size_t)NN * H_D);
    float* x2a = alloc((size_t)NN * H_D);
    float* x1b = alloc((size_t)NN * H_D);
    float* x2b = alloc((size_t)NN * H_D);
    float* esed = alloc(4 * NN);
    float* es1 = esed, *es2 = esed + NN, *ed1 = esed + 2 * NN, *ed2 = esed + 3 * NN;
    float* co1a = alloc(NN * 3);
    float* co1b = alloc(NN * 3);
    float* co2a = alloc(NN * 3);
    float* co2b = alloc(NN * 3);
    float* macc1 = alloc((size_t)NN * M_D);
    float* macc2 = alloc((size_t)NN * M_D);
    unsigned* A16a = (unsigned*)alloc((size_t)NN * BUPAD);
    unsigned* B16a = (unsigned*)alloc((size_t)NN * BUPAD);
    unsigned* A16b = (unsigned*)alloc((size_t)NN * BUPAD);
    unsigned* B16b = (unsigned*)alloc((size_t)NN * BUPAD);
    unsigned* h16a = (unsigned*)alloc((size_t)NN * 64);
    unsigned* h16b = (unsigned*)alloc((size_t)NN * 64);
    int* cnt4 = (int*)alloc(4 * NN);
    int* rp4 = (int*)alloc(4 * (NN + 1));
    int* cjI1 = (int*)alloc(EIA_D);
    int* cjI2 = (int*)alloc(EIA_D);
    int* cj12 = (int*)alloc(EIR_D);
    int* cj21 = (int*)alloc(EIR_D);
    int* dstI1 = (int*)alloc(EIA_D);
    int* dstI2 = (int*)alloc(EIA_D);
    int* iota = (int*)alloc(NN);
    unsigned short* Wt = (unsigned short*)alloc(1100000);
    unsigned short* Wf = (unsigned short*)alloc(45000);
    unsigned short* me16a = (unsigned short*)alloc((size_t)EIA_D * 8);
    unsigned short* me16b = (unsigned short*)alloc((size_t)EIA_D * 8);
    float* cveca = alloc((size_t)EIA_D * 3);
    float* cvecb = alloc((size_t)EIA_D * 3);
    float* nh1 = (float*)B16a;     // alias: B tables dead post-edge; pad cols re-zeroed each rebuild
    float* nh2 = (float*)B16b;
    float* Hb  = (float*)A16a;     // alias: table block dead at aux time

    const int N = NN, H = H_D;
    int gNW = (N + 3) / 4;
    int gEA = (EIA_D + 255) / 256;

    // ---- weight prep ----
    PrepArgs pa;
    unsigned woffs[29], wsz[29];
    unsigned wo = 0;
    int wi = 0;
    auto addw = [&](const float* src, int K, int Ncols) {
        int Kpad = (K + 31) & ~31;
        int Npad = (Ncols + 63) & ~63;
        pa.d[wi] = {src, wo, K, Ncols, Kpad, Npad};
        woffs[wi] = wo; wsz[wi] = (unsigned)(Npad * Kpad);
        wo += 2u * Npad * Kpad;
        ++wi;
    };
    addw(g0_w, FIN_D, H);                          // 0
    addw(g0_w + FIN_D * H, FIN_D, H);              // 1
    addw(g1_w, H, H);                              // 2
    addw(g1_w + H * H, H, H);                      // 3
    for (int p = 0; p < 4; ++p) addw(it_ws + (size_t)p * H * H, H, H);   // 4..7
    for (int p = 0; p < 4; ++p) addw(it_wd + (size_t)p * H * H, H, H);   // 8..11
    for (int p = 0; p < 4; ++p) {                  // 12..19
        const float* ew1 = eg_e_w1 + (size_t)p * EIN_D * EHID_D;
        addw(ew1, H, EHID_D);
        addw(ew1 + (size_t)H * EHID_D, H, EHID_D);
    }
    for (int p = 0; p < 4; ++p) addw(eg_n_w1 + (size_t)p * NIN_D * NHID_D, NIN_D, NHID_D);  // 20..23
    for (int p = 0; p < 4; ++p) addw(eg_n_w2 + (size_t)p * NHID_D * H, NHID_D, H);          // 24..27
    addw(aux_w1, 2 * H, H);                        // 28
    k_prep<<<dim3(29, 16), 256, 0, stream>>>(pa, Wt);
    k_prep_ew2<<<4, 256, 0, stream>>>(eg_e_w2, eg_c_w1, Wf);
    auto WH = [&](int i) { return (const unsigned short*)(Wt + woffs[i]); };
    auto WL = [&](int i) { return (const unsigned short*)(Wt + woffs[i] + wsz[i]); };

    // ---- CSRs + iota ----
    k_filli<<<(4 * N + 255) / 256, 256, 0, stream>>>(cnt4, 0, 4 * N);
    k_iota<<<(N + 255) / 256, 256, 0, stream>>>(iota, N);
    k_hist<<<gEA, 256, 0, stream>>>(ei_intra1 + EIA_D, EIA_D, cnt4);
    k_hist<<<gEA, 256, 0, stream>>>(ei_intra2 + EIA_D, EIA_D, cnt4 + N);
    k_hist<<<gEA, 256, 0, stream>>>(ei_12 + EIR_D, EIR_D, cnt4 + 2 * N);
    k_hist<<<gEA, 256, 0, stream>>>(ei_21 + EIR_D, EIR_D, cnt4 + 3 * N);
    k_scan4<<<4, 256, 0, stream>>>(cnt4, N, rp4);
    k_filli<<<(4 * N + 255) / 256, 256, 0, stream>>>(cnt4, 0, 4 * N);
    const int* rpI1 = rp4;
    const int* rpI2 = rp4 + (N + 1);
    const int* rp12 = rp4 + 2 * (N + 1);
    const int* rp21 = rp4 + 3 * (N + 1);
    k_scatter<<<gEA, 256, 0, stream>>>(ei_intra1, ei_intra1 + EIA_D, EIA_D, rpI1, cnt4, cjI1, dstI1);
    k_scatter<<<gEA, 256, 0, stream>>>(ei_intra2, ei_intra2 + EIA_D, EIA_D, rpI2, cnt4 + N, cjI2, dstI2);
    k_scatter<<<gEA, 256, 0, stream>>>(ei_12, ei_12 + EIR_D, EIR_D, rp12, cnt4 + 2 * N, cj12, nullptr);
    k_scatter<<<gEA, 256, 0, stream>>>(ei_21, ei_21 + EIR_D, EIR_D, rp21, cnt4 + 3 * N, cj21, nullptr);

    const int MB = (N + 127) / 128;   // 157
    MMJobs js{};

    // ---- GAT intra layers ----
    auto intraL = [&](auto kt_tag, const float* xa, const float* xb, int wa, int wb,
                      const float* as_a, const float* ad_a, const float* as_b, const float* ad_b,
                      const float* b_a, const float* b_b, float* oa, float* ob) {
        constexpr int KT = decltype(kt_tag)::value;
        js.j[0] = {xa, nullptr, nullptr, nullptr, WH(wa), WL(wa), nullptr, nullptr,
                   nullptr, (unsigned short*)h16a, as_a, ad_a, es1, ed1};
        js.j[1] = {xb, nullptr, nullptr, nullptr, WH(wb), WL(wb), nullptr, nullptr,
                   nullptr, (unsigned short*)h16b, as_b, ad_b, es2, ed2};
        k_mmf<0, false, 2, true, KT, false, false><<<dim3(MB, 1, 2), 256, 0, stream>>>(
            js, N, H, H, 2, KT * 32, 0);
        GatJob g0{rpI1, cjI1, 1, es1, ed1, h16a, b_a, oa};
        GatJob g1{rpI2, cjI2, 1, es2, ed2, h16b, b_b, ob};
        k_gat2<<<dim3(gNW, 2), 256, 0, stream>>>(g0, g1, N);
    };

    intraL(std::integral_constant<int, 2>{}, x1_in, x2_in, 0, 1,
           g0_as, g0_ad, g0_as + H, g0_ad + H, g0_b, g0_b + H, x1a, x2a);
    const float* cx1 = x1a;
    const float* cx2 = x2a;
    intraL(std::integral_constant<int, 4>{}, cx1, cx2, 2, 3,
           g1_as, g1_ad, g1_as + H, g1_ad + H, g1_b, g1_b + H, x1b, x2b);
    cx1 = x1b; cx2 = x2b;

    // ---- GAT cross layers: hs+hd in ONE z=4 launch ----
    {
        float* outs1[2] = {x1a, x1b};
        float* outs2[2] = {x2a, x2b};
        for (int l = 0; l < 2; ++l) {
            int p0 = l * 2 + 0, p1 = l * 2 + 1;
            float* o2 = outs2[l];
            float* o1 = outs1[l];
            js.j[0] = {cx1, nullptr, nullptr, nullptr, WH(4 + p0), WL(4 + p0), nullptr, nullptr,
                       nullptr, (unsigned short*)h16a, it_as + p0 * H, nullptr, es1, nullptr};
            js.j[1] = {cx2, nullptr, nullptr, nullptr, WH(4 + p1), WL(4 + p1), nullptr, nullptr,
                       nullptr, (unsigned short*)h16b, it_as + p1 * H, nullptr, es2, nullptr};
            js.j[2] = {cx2, nullptr, nullptr, nullptr, WH(8 + p0), WL(8 + p0), nullptr, nullptr,
                       nullptr, nullptr, it_ad + p0 * H, nullptr, ed1, nullptr};
            js.j[3] = {cx1, nullptr, nullptr, nullptr, WH(8 + p1), WL(8 + p1), nullptr, nullptr,
                       nullptr, nullptr, it_ad + p1 * H, nullptr, ed2, nullptr};
            k_mmf<0, false, 1, true, 4, false, false><<<dim3(MB, 1, 4), 256, 0, stream>>>(
                js, N, H, H, 2, 128, 0);
            GatJob g0{rp12, cj12, 0, es1, ed1, h16a, it_b + p0 * H, o2};
            GatJob g1{rp21, cj21, 0, es2, ed2, h16b, it_b + p1 * H, o1};
            k_gat2<<<dim3(gNW, 2), 256, 0, stream>>>(g0, g1, N);
            cx1 = o1; cx2 = o2;
        }
    }

    // ---- EGNN layers ----
    auto egnn_pair = [&](const float* f1, const float* f2, const float* c1, const float* c2,
                         int l, float* fo1, float* fo2, float* co1, float* co2) {
        int p0 = 2 * l, p1 = 2 * l + 1;
        js.j[0] = {f1, nullptr, nullptr, nullptr, WH(12 + 2 * p0), WL(12 + 2 * p0),
                   eg_e_b1 + p0 * EHID_D, nullptr, (float*)A16a, nullptr, nullptr, nullptr, nullptr, nullptr};
        js.j[1] = {f1, nullptr, nullptr, nullptr, WH(13 + 2 * p0), WL(13 + 2 * p0),
                   nullptr, nullptr, (float*)B16a, nullptr, nullptr, nullptr, nullptr, nullptr};
        js.j[2] = {f2, nullptr, nullptr, nullptr, WH(12 + 2 * p1), WL(12 + 2 * p1),
                   eg_e_b1 + p1 * EHID_D, nullptr, (float*)A16b, nullptr, nullptr, nullptr, nullptr, nullptr};
        js.j[3] = {f2, nullptr, nullptr, nullptr, WH(13 + 2 * p1), WL(13 + 2 * p1),
                   nullptr, nullptr, (float*)B16b, nullptr, nullptr, nullptr, nullptr, nullptr};
        k_mmf<0, true, 0, false, 4, false, false><<<dim3(MB, 1, 4), 256, 0, stream>>>(
            js, N, EHID_D, APAD, 9, 128, 0);
        const float* ew1a = eg_e_w1 + (size_t)p0 * EIN_D * EHID_D;
        const float* ew1b = eg_e_w1 + (size_t)p1 * EIN_D * EHID_D;
        EJob e0{dstI1, cjI1, A16a, B16a, c1, ew1a + (size_t)256 * EHID_D,
                Wf + (size_t)p0 * 8704, Wf + 4 * 8704 + (size_t)p0 * 8704,
                Wf + 69632 + (size_t)p0 * 4096, Wf + 69632 + (size_t)p0 * 4096 + 2048,
                eg_e_b2 + p0 * M_D, eg_c_b1 + p0 * 64,
                eg_c_w2 + p0 * 64, eg_c_b2 + p0, me16a, cveca};
        EJob e1{dstI2, cjI2, A16b, B16b, c2, ew1b + (size_t)256 * EHID_D,
                Wf + (size_t)p1 * 8704, Wf + 4 * 8704 + (size_t)p1 * 8704,
                Wf + 69632 + (size_t)p1 * 4096, Wf + 69632 + (size_t)p1 * 4096 + 2048,
                eg_e_b2 + p1 * M_D, eg_c_b1 + p1 * 64,
                eg_c_w2 + p1 * 64, eg_c_b2 + p1, me16b, cvecb};
        k_edge2<<<dim3((EIA_D + 63) / 64, 2), 256, 0, stream>>>(e0, e1, EIA_D);
        SJob s0{rpI1, me16a, cveca, c1, co1, macc1};
        SJob s1{rpI2, me16b, cvecb, c2, co2, macc2};
        k_seg2<<<dim3(gNW, 2), 256, 0, stream>>>(s0, s1, N);
        // nh: full-K resident gather-concat [feats(128) | macc(16)], Kact=144 (pad strip zeroed)
        js.j[0] = {f1, macc1, iota, iota, WH(20 + p0), WL(20 + p0),
                   eg_n_b1 + p0 * NHID_D, nullptr, nh1, nullptr, nullptr, nullptr, nullptr, nullptr};
        js.j[1] = {f2, macc2, iota, iota, WH(20 + p1), WL(20 + p1),
                   eg_n_b1 + p1 * NHID_D, nullptr, nh2, nullptr, nullptr, nullptr, nullptr, nullptr};
        k_mmf<2, false, 0, false, 5, true, false><<<dim3(MB, 1, 2), 256, 0, stream>>>(
            js, N, NHID_D, NHID_D, 4, NIN_D, M_D);
        // n_w2: full-K (K=256) + residual
        js.j[0] = {nh1, nullptr, nullptr, nullptr, WH(24 + p0), WL(24 + p0),
                   eg_n_b2 + p0 * H, f1, fo1, nullptr, nullptr, nullptr, nullptr, nullptr};
        js.j[1] = {nh2, nullptr, nullptr, nullptr, WH(24 + p1), WL(24 + p1),
                   eg_n_b2 + p1 * H, f2, fo2, nullptr, nullptr, nullptr, nullptr, nullptr};
        k_mmf<0, false, 0, false, 8, false, true><<<dim3(MB, 1, 2), 256, 0, stream>>>(
            js, N, H, H, 2, NHID_D, 0);
    };
    egnn_pair(cx1, cx2, pos1, pos2, 0, x1a, x2a, co1a, co2a);
    cx1 = x1a; cx2 = x2a;
    egnn_pair(cx1, cx2, co1a, co2a, 1, x1b, x2b, co1b, co2b);
    cx1 = x1b; cx2 = x2b;

    // ---- heads ----
    k_nodescore<<<gNW, 2 * 128, 0, stream>>>(cx1, lin_w, lin_b, dout, N);
    k_nodescore<<<gNW, 2 * 128, 0, stream>>>(cx2, lin_w, lin_b, dout + N, N);
    js.j[0] = {cx1, cx2, ei_int, ei_int + EIT_D, WH(28), WL(28),
               aux_b1, nullptr, Hb, nullptr, nullptr, nullptr, nullptr, nullptr};
    k_mmf<1, false, 0, false, 8, true, false><<<dim3((EIT_D + 127) / 128, 1, 1), 256, 0, stream>>>(
        js, EIT_D, H, H, 2, 2 * H, H_D);
    k_dist<<<(EIT_D + 3) / 4, 256, 0, stream>>>(Hb, aux_w2, aux_b2, dout + 2 * N, EIT_D);
}

// Round 14
// 1458.101 us; speedup vs baseline: 1.0286x; 1.0286x over previous
//
#include <hip/hip_runtime.h>
#include <hip/hip_bf16.h>
#include <cstdint>
#include <cstddef>
#include <type_traits>

// ---- problem constants ----
#define NN     20000
#define FIN_D  64
#define H_D    128
#define M_D    16
#define EIA_D  256000
#define EIR_D  256000
#define EIT_D  100000
#define EIN_D  257
#define EHID_D 514
#define NIN_D  144
#define NHID_D 256
#define APAD   544          // padded EHID; 17 k-tiles of 32
#define BUPAD  272          // APAD/2 uints per bf16 row (A and B tables)

typedef short bfrag __attribute__((ext_vector_type(8)));   // 8 bf16 (4 VGPRs)
typedef float ffrag __attribute__((ext_vector_type(4)));   // 4 fp32 acc

__device__ __forceinline__ float siluf(float x) {
    return x * __builtin_amdgcn_rcpf(1.f + __expf(-x));
}
__device__ __forceinline__ float reluf(float x) { return x > 0.f ? x : 0.f; }
__device__ __forceinline__ unsigned short f2bf(float f) {  // RNE fp32->bf16
    unsigned u = __float_as_uint(f);
    return (unsigned short)((u + 0x7FFFu + ((u >> 16) & 1u)) >> 16);
}
__device__ __forceinline__ float bf2f(unsigned short h) { return __uint_as_float(((unsigned)h) << 16); }
__device__ __forceinline__ float bf_lo(unsigned u) { return __uint_as_float(u << 16); }
__device__ __forceinline__ float bf_hi(unsigned u) { return __uint_as_float(u & 0xFFFF0000u); }
__device__ __forceinline__ unsigned pkbf(float f0, float f1) {
    __hip_bfloat162 h = __float22bfloat162_rn(make_float2(f0, f1));
    return *(unsigned*)&h;
}

// ---------------- CSR build ----------------
__global__ void k_filli(int* p, int v, int n) {
    int i = blockIdx.x * 256 + threadIdx.x; if (i < n) p[i] = v;
}
__global__ void k_iota(int* p, int n) {
    int i = blockIdx.x * 256 + threadIdx.x; if (i < n) p[i] = i;
}
__global__ void k_hist(const int* __restrict__ si, int nE, int* __restrict__ cnt) {
    int e = blockIdx.x * 256 + threadIdx.x; if (e < nE) atomicAdd(&cnt[si[e]], 1);
}
__global__ void k_scan4(const int* __restrict__ cnt4, int n, int* __restrict__ rp4) {
    const int* cnt = cnt4 + (size_t)blockIdx.x * n;
    int* rp = rp4 + (size_t)blockIdx.x * (n + 1);
    __shared__ int tmp[256];
    __shared__ int carry;
    if (threadIdx.x == 0) { carry = 0; rp[0] = 0; }
    __syncthreads();
    for (int base = 0; base < n; base += 256) {
        int i = base + threadIdx.x;
        int v = (i < n) ? cnt[i] : 0;
        tmp[threadIdx.x] = v;
        __syncthreads();
        for (int off = 1; off < 256; off <<= 1) {
            int t = (threadIdx.x >= off) ? tmp[threadIdx.x - off] : 0;
            __syncthreads();
            tmp[threadIdx.x] += t;
            __syncthreads();
        }
        if (i < n) rp[i + 1] = carry + tmp[threadIdx.x];
        __syncthreads();
        if (threadIdx.x == 0) carry += tmp[255];
        __syncthreads();
    }
}
__global__ void k_scatter(const int* __restrict__ sj, const int* __restrict__ si, int nE,
                          const int* __restrict__ rp, int* __restrict__ cursor,
                          int* __restrict__ colj, int* __restrict__ dsti) {
    int e = blockIdx.x * 256 + threadIdx.x;
    if (e >= nE) return;
    int i = si[e];
    int p = rp[i] + atomicAdd(&cursor[i], 1);
    colj[p] = sj[e];
    if (dsti) dsti[p] = i;
}

// ---------------- weight prep: transpose + hi/lo bf16 split ----------------
struct PrepDesc { const float* src; unsigned dstOff; int K, N, Kpad, Npad; };
struct PrepArgs { PrepDesc d[29]; };
__global__ void k_prep(PrepArgs pa, unsigned short* __restrict__ Wt) {
    PrepDesc de = pa.d[blockIdx.x];
    int tot = de.Npad * de.Kpad;
    unsigned short* hi = Wt + de.dstOff;
    unsigned short* lo = hi + tot;
    for (int i = blockIdx.y * 256 + threadIdx.x; i < tot; i += gridDim.y * 256) {
        int n = i / de.Kpad, k = i - n * de.Kpad;
        float v = (n < de.N && k < de.K) ? de.src[(size_t)k * de.N + n] : 0.f;
        unsigned short h = f2bf(v);
        hi[i] = h;
        lo[i] = f2bf(v - bf2f(h));
    }
}

// ew2 [514][16] -> MFMA B-frag order (zero beyond k>=514); cw1 [16][64] -> gate B-frags
__global__ void k_prep_ew2(const float* __restrict__ eg_e_w2, const float* __restrict__ eg_c_w1,
                           unsigned short* __restrict__ Wf) {
    int pidx = blockIdx.x;
    const float* src = eg_e_w2 + (size_t)pidx * EHID_D * M_D;
    unsigned short* hi = Wf + (size_t)pidx * 8704;
    unsigned short* lo = Wf + 4 * 8704 + (size_t)pidx * 8704;
    for (int idx = threadIdx.x; idx < 8704; idx += 256) {
        int t = idx >> 9, rem = idx & 511;
        int lane = rem >> 3, j2 = rem & 7;
        int k = t * 32 + ((lane >> 4) << 3) + j2;
        int n = lane & 15;
        float v = (k < EHID_D) ? src[(size_t)k * 16 + n] : 0.f;
        unsigned short h = f2bf(v);
        hi[idx] = h;
        lo[idx] = f2bf(v - bf2f(h));
    }
    const float* cw1 = eg_c_w1 + (size_t)pidx * 16 * 64;
    unsigned short* ghi = Wf + 69632 + (size_t)pidx * 4096;
    unsigned short* glo = ghi + 2048;
    for (int idx = threadIdx.x; idx < 2048; idx += 256) {
        int nt = idx >> 9, rem = idx & 511;
        int lane = rem >> 3, j = rem & 7;
        int q = lane >> 4, mm = lane & 15;
        int k = q * 8 + j;
        float v = (k < 16) ? cw1[(size_t)k * 64 + nt * 16 + mm] : 0.f;
        unsigned short h = f2bf(v);
        ghi[idx] = h;
        glo[idx] = f2bf(v - bf2f(h));
    }
}

struct MMJob {
    const float* A; const float* A2;
    const int* gi0; const int* gi1;
    const unsigned short* Wh; const unsigned short* Wl;
    const float* bias; const float* res;
    float* C; unsigned short* C2;
    const float* da; const float* db;
    float* dota; float* dotb;
};
struct MMJobs { MMJob j[4]; };

// ---------------- full-K resident MFMA GEMM (K = KT*32 <= 160; LDS <= 40KB, 4 blk/CU) -------
// A staged once in LDS (bf16), bn tiles looped internally. DOT: direct-store per-row dots.
// GATHER: row = [A[gi0](128) | A2[gi1](stride s2)]; strips beyond Kact zeroed (NaN-pad lesson).
// OBF pad cols Nc..ldc-1 zeroed. NOTE: KT=8 (64KB LDS) regressed in round 13 — 2 blk/CU
// occupancy cliff; keep KT<=5 here and use k_mm for K>160.
template<int ACT, bool OBF, int DOT, bool NOC, int KT, bool GATHER>
__global__ __launch_bounds__(256) void k_mmf(MMJobs js, int M, int Nc, int ldc, int nbn,
                                             int Kact, int s2) {
    constexpr int K = KT * 32;
    __shared__ __align__(16) unsigned short sAh[128 * K];
    const MMJob jb = js.j[blockIdx.z];
    const int tid = threadIdx.x;
    const int bm = blockIdx.x * 128;
    const int wv = tid >> 6, lane = tid & 63;
    const int q = lane >> 4, mm = lane & 15;
    const int sr = tid >> 1;
    const int sks = (tid & 1) * 16;
    const int gm_s = bm + sr;
    const int sgmt = sr >> 4, smm = sr & 15, qb = (tid & 1) * 2;
    int gidx0 = 0, gidx1 = 0;
    if (GATHER && gm_s < M) { gidx0 = jb.gi0[gm_s]; gidx1 = jb.gi1[gm_s]; }
#pragma unroll
    for (int t = 0; t < KT; ++t) {
        float v[16];
        int kk = t * 32 + sks;
        bool valid = (gm_s < M) && (kk < Kact);
        if (valid) {
            const float* src;
            if (GATHER) src = (kk < 128) ? (jb.A + (size_t)gidx0 * 128 + kk)
                                         : (jb.A2 + (size_t)gidx1 * s2 + (kk - 128));
            else src = jb.A + (size_t)gm_s * K + kk;
#pragma unroll
            for (int i = 0; i < 4; ++i) {
                float4 t4 = ((const float4*)src)[i];
                v[4 * i] = t4.x; v[4 * i + 1] = t4.y; v[4 * i + 2] = t4.z; v[4 * i + 3] = t4.w;
            }
        } else {
#pragma unroll
            for (int i = 0; i < 16; ++i) v[i] = 0.f;
        }
#pragma unroll
        for (int o = 0; o < 2; ++o) {
            unsigned hw[4];
#pragma unroll
            for (int p = 0; p < 4; ++p)
                hw[p] = pkbf(v[o * 8 + 2 * p], v[o * 8 + 2 * p + 1]);
            int off16 = ((sgmt * KT + t) * 4 + qb + o) * 16 + smm;
            ((uint4*)sAh)[off16] = make_uint4(hw[0], hw[1], hw[2], hw[3]);
        }
    }
    __syncthreads();
    float dra[2][4] = {}, drb[2][4] = {};
    for (int b = 0; b < nbn; ++b) {
        const int bn = b * 64;
        ffrag acc[2][4];
#pragma unroll
        for (int mt = 0; mt < 2; ++mt)
#pragma unroll
            for (int nt = 0; nt < 4; ++nt)
#pragma unroll
                for (int r = 0; r < 4; ++r) acc[mt][nt][r] = 0.f;
#pragma unroll
        for (int t = 0; t < KT; ++t) {
            bfrag bh[4], bl[4];
#pragma unroll
            for (int nt = 0; nt < 4; ++nt) {
                size_t woff = (size_t)(bn + nt * 16 + mm) * K + t * 32 + q * 8;
                bh[nt] = *(const bfrag*)(jb.Wh + woff);
                bl[nt] = *(const bfrag*)(jb.Wl + woff);
            }
#pragma unroll
            for (int mt = 0; mt < 2; ++mt) {
                int off16 = (((wv * 2 + mt) * KT + t) * 4 + q) * 16 + mm;
                bfrag ah = ((const bfrag*)sAh)[off16];
#pragma unroll
                for (int nt = 0; nt < 4; ++nt) {
                    acc[mt][nt] = __builtin_amdgcn_mfma_f32_16x16x32_bf16(ah, bh[nt], acc[mt][nt], 0, 0, 0);
                    acc[mt][nt] = __builtin_amdgcn_mfma_f32_16x16x32_bf16(ah, bl[nt], acc[mt][nt], 0, 0, 0);
                }
            }
        }
        if (DOT >= 1) {
            float dav[4], dbv[4];
#pragma unroll
            for (int nt = 0; nt < 4; ++nt) {
                int gn = bn + nt * 16 + mm;
                dav[nt] = (gn < Nc) ? jb.da[gn] : 0.f;
                if (DOT == 2) dbv[nt] = (gn < Nc) ? jb.db[gn] : 0.f;
            }
#pragma unroll
            for (int mt = 0; mt < 2; ++mt)
#pragma unroll
                for (int r = 0; r < 4; ++r)
#pragma unroll
                    for (int nt = 0; nt < 4; ++nt) {
                        dra[mt][r] += acc[mt][nt][r] * dav[nt];
                        if (DOT == 2) drb[mt][r] += acc[mt][nt][r] * dbv[nt];
                    }
        }
        const bool doC2 = jb.C2 != nullptr;
        if (!NOC || doC2) {
#pragma unroll
            for (int mt = 0; mt < 2; ++mt) {
#pragma unroll
                for (int nt = 0; nt < 4; ++nt) {
                    int gn = bn + nt * 16 + mm;
                    bool inb = gn < Nc;
                    bool padz = OBF && !NOC && !inb && gn < ldc;
                    if (!inb && !padz) continue;
#pragma unroll
                    for (int r = 0; r < 4; ++r) {
                        int gm = bm + wv * 32 + mt * 16 + q * 4 + r;
                        if (gm >= M) continue;
                        if (padz) {
                            ((unsigned short*)jb.C)[(size_t)gm * ldc + gn] = 0;
                            continue;
                        }
                        float vv = acc[mt][nt][r];
                        if (jb.bias) vv += jb.bias[gn];
                        if (ACT == 1) vv = reluf(vv);
                        if (ACT == 2) vv = siluf(vv);
                        if (!NOC) {
                            if (OBF) ((unsigned short*)jb.C)[(size_t)gm * ldc + gn] = f2bf(vv);
                            else jb.C[(size_t)gm * ldc + gn] = vv;
                        }
                        if (doC2) jb.C2[(size_t)gm * ldc + gn] = f2bf(vv);
                    }
                }
            }
        }
    }
    if (DOT >= 1) {
#pragma unroll
        for (int mt = 0; mt < 2; ++mt)
#pragma unroll
            for (int r = 0; r < 4; ++r) {
                float sa = dra[mt][r];
                sa += __shfl_xor(sa, 1); sa += __shfl_xor(sa, 2);
                sa += __shfl_xor(sa, 4); sa += __shfl_xor(sa, 8);
                float sb = 0.f;
                if (DOT == 2) {
                    sb = drb[mt][r];
                    sb += __shfl_xor(sb, 1); sb += __shfl_xor(sb, 2);
                    sb += __shfl_xor(sb, 4); sb += __shfl_xor(sb, 8);
                }
                int gm = bm + wv * 32 + mt * 16 + q * 4 + r;
                if (mm == 0 && gm < M) {
                    jb.dota[gm] = sa;
                    if (DOT == 2) jb.dotb[gm] = sb;
                }
            }
    }
}

// ---------------- general MFMA GEMM (AMODE=2 hi/lo, K>160 paths: nw2, aux) ----------------
template<int ACT, bool RES, bool GATHER>
__global__ __launch_bounds__(256) void k_mm(MMJobs js, int M, int Nc, int K, int Kpad, int ldc, int s2) {
    __shared__ __align__(16) unsigned short sAh[128 * 32];
    __shared__ __align__(16) unsigned short sAl[128 * 32];
    const MMJob jb = js.j[blockIdx.z];
    const int tid = threadIdx.x;
    const int bm = blockIdx.x * 128, bn = blockIdx.y * 64;
    const int wv = tid >> 6, lane = tid & 63;
    ffrag acc[2][4];
#pragma unroll
    for (int mt = 0; mt < 2; ++mt)
#pragma unroll
        for (int nt = 0; nt < 4; ++nt)
#pragma unroll
            for (int r = 0; r < 4; ++r) acc[mt][nt][r] = 0.f;
    const int sr = tid >> 1;
    const int sks = (tid & 1) * 16;
    const int gm_s = bm + sr;
    const int sgmt = sr >> 4, smm = sr & 15, qb = (tid & 1) * 2;
    int gidx0 = 0, gidx1 = 0;
    if (GATHER && gm_s < M) { gidx0 = jb.gi0[gm_s]; gidx1 = jb.gi1[gm_s]; }
    const int q = lane >> 4, mm = lane & 15;

    for (int k0 = 0; k0 < Kpad; k0 += 32) {
        float v[16];
        bool valid = (gm_s < M) && (k0 + sks < K);
        if (valid) {
            const float* src;
            int kk = k0 + sks;
            if (GATHER) src = (kk < 128) ? (jb.A + (size_t)gidx0 * 128 + kk)
                                         : (jb.A2 + (size_t)gidx1 * s2 + (kk - 128));
            else src = jb.A + (size_t)gm_s * K + kk;
#pragma unroll
            for (int i = 0; i < 4; ++i) {
                float4 t4 = ((const float4*)src)[i];
                v[4 * i] = t4.x; v[4 * i + 1] = t4.y; v[4 * i + 2] = t4.z; v[4 * i + 3] = t4.w;
            }
        } else {
#pragma unroll
            for (int i = 0; i < 16; ++i) v[i] = 0.f;
        }
#pragma unroll
        for (int o = 0; o < 2; ++o) {
            unsigned hw[4], lw[4];
#pragma unroll
            for (int p = 0; p < 4; ++p) {
                float f0 = v[o * 8 + 2 * p], f1 = v[o * 8 + 2 * p + 1];
                unsigned short h0 = f2bf(f0), h1 = f2bf(f1);
                unsigned short l0 = f2bf(f0 - bf2f(h0)), l1 = f2bf(f1 - bf2f(h1));
                hw[p] = (unsigned)h0 | ((unsigned)h1 << 16);
                lw[p] = (unsigned)l0 | ((unsigned)l1 << 16);
            }
            int off16 = (sgmt * 4 + qb + o) * 16 + smm;
            ((uint4*)sAh)[off16] = make_uint4(hw[0], hw[1], hw[2], hw[3]);
            ((uint4*)sAl)[off16] = make_uint4(lw[0], lw[1], lw[2], lw[3]);
        }
        __syncthreads();
        bfrag bh[4], bl[4];
#pragma unroll
        for (int nt = 0; nt < 4; ++nt) {
            size_t woff = (size_t)(bn + nt * 16 + mm) * Kpad + k0 + q * 8;
            bh[nt] = *(const bfrag*)(jb.Wh + woff);
            bl[nt] = *(const bfrag*)(jb.Wl + woff);
        }
#pragma unroll
        for (int mt = 0; mt < 2; ++mt) {
            int off16 = ((wv * 2 + mt) * 4 + q) * 16 + mm;
            bfrag ah = ((const bfrag*)sAh)[off16];
            bfrag al = ((const bfrag*)sAl)[off16];
#pragma unroll
            for (int nt = 0; nt < 4; ++nt) {
                acc[mt][nt] = __builtin_amdgcn_mfma_f32_16x16x32_bf16(ah, bh[nt], acc[mt][nt], 0, 0, 0);
                acc[mt][nt] = __builtin_amdgcn_mfma_f32_16x16x32_bf16(ah, bl[nt], acc[mt][nt], 0, 0, 0);
                acc[mt][nt] = __builtin_amdgcn_mfma_f32_16x16x32_bf16(al, bh[nt], acc[mt][nt], 0, 0, 0);
            }
        }
        __syncthreads();
    }
#pragma unroll
    for (int mt = 0; mt < 2; ++mt) {
#pragma unroll
        for (int nt = 0; nt < 4; ++nt) {
            int gn = bn + nt * 16 + mm;
            if (gn >= Nc) continue;
#pragma unroll
            for (int r = 0; r < 4; ++r) {
                int gm = bm + wv * 32 + mt * 16 + q * 4 + r;
                if (gm >= M) continue;
                float vv = acc[mt][nt][r];
                if (jb.bias) vv += jb.bias[gn];
                if (ACT == 1) vv = reluf(vv);
                if (ACT == 2) vv = siluf(vv);
                if (RES) vv += jb.res[(size_t)gm * Nc + gn];
                jb.C[(size_t)gm * ldc + gn] = vv;
            }
        }
    }
}

__global__ void k_nodescore(const float* __restrict__ x, const float* __restrict__ wv,
                            const float* __restrict__ b, float* __restrict__ o, int n) {
    int w = blockIdx.x * 4 + (threadIdx.x >> 6);
    int lane = threadIdx.x & 63;
    if (w >= n) return;
    const float* r = x + (size_t)w * H_D;
    float s = r[lane] * wv[lane] + r[lane + 64] * wv[lane + 64];
#pragma unroll
    for (int off = 32; off; off >>= 1) s += __shfl_xor(s, off);
    if (lane == 0) o[w] = s + b[0];
}

// ---------------- fused GAT softmax-aggregate: both graphs per launch, 4-edge unroll --------
struct GatJob {
    const int* rp; const int* cj; int hasSelf;
    const float* es; const float* ed;
    const unsigned* h16; const float* bias; float* out;
};
__global__ __launch_bounds__(256) void k_gat2(GatJob j0, GatJob j1, int N) {
    const GatJob jb = blockIdx.y ? j1 : j0;
    int node = blockIdx.x * 4 + (threadIdx.x >> 6);
    int lane = threadIdx.x & 63;
    if (node >= N) return;
    int start = jb.rp[node], end = jb.rp[node + 1];
    float edi = jb.ed[node];
    float den = 0.f, a0 = 0.f, a1 = 0.f;
    int p = start;
    for (; p + 4 <= end; p += 4) {
        int j[4]; float e[4]; unsigned u[4];
#pragma unroll
        for (int x = 0; x < 4; ++x) j[x] = jb.cj[p + x];
#pragma unroll
        for (int x = 0; x < 4; ++x) { e[x] = jb.es[j[x]]; u[x] = jb.h16[(size_t)j[x] * 64 + lane]; }
#pragma unroll
        for (int x = 0; x < 4; ++x) {
            float v = e[x] + edi;
            v = v < 0.f ? 0.2f * v : v;
            float ex = __expf(v);
            den += ex;
            a0 += ex * bf_lo(u[x]);
            a1 += ex * bf_hi(u[x]);
        }
    }
    for (; p < end; ++p) {
        int j = jb.cj[p];
        float v = jb.es[j] + edi;
        v = v < 0.f ? 0.2f * v : v;
        float ex = __expf(v);
        den += ex;
        unsigned u = jb.h16[(size_t)j * 64 + lane];
        a0 += ex * bf_lo(u);
        a1 += ex * bf_hi(u);
    }
    if (jb.hasSelf) {
        float v = jb.es[node] + edi;
        v = v < 0.f ? 0.2f * v : v;
        float ex = __expf(v);
        den += ex;
        unsigned u = jb.h16[(size_t)node * 64 + lane];
        a0 += ex * bf_lo(u);
        a1 += ex * bf_hi(u);
    }
    float inv = 1.f / (den + 1e-16f);
    float2 o;
    o.x = reluf(a0 * inv + jb.bias[2 * lane]);
    o.y = reluf(a1 * inv + jb.bias[2 * lane + 1]);
    ((float2*)(jb.out + (size_t)node * H_D))[lane] = o;
}

// ---------------- EGNN edge kernel: both graphs per launch; MFMA gate ----------------
struct EJob {
    const int* dsti; const int* cj;
    const unsigned* A16; const unsigned* Bp; const float* coors;
    const float* w_rd;
    const unsigned short* Wfh; const unsigned short* Wfl;
    const unsigned short* Wgh; const unsigned short* Wgl;
    const float* eb2; const float* cb1;
    const float* cw2; const float* cb2;
    unsigned short* me16; float* cvec;
};
__global__ __launch_bounds__(256) void k_edge2(EJob e0, EJob e1, int nE) {
    const EJob jb = blockIdx.y ? e1 : e0;
    __shared__ __align__(16) float s_w[APAD];
    __shared__ float s_cb1[64], s_cw2[64], s_eb2[16];
    __shared__ __align__(16) float sM[4][16][20];
    for (int i = threadIdx.x; i < APAD; i += 256)
        s_w[i] = (i < EHID_D) ? jb.w_rd[i] : 0.f;
    if (threadIdx.x < 64) { s_cb1[threadIdx.x] = jb.cb1[threadIdx.x]; s_cw2[threadIdx.x] = jb.cw2[threadIdx.x]; }
    if (threadIdx.x < 16) s_eb2[threadIdx.x] = jb.eb2[threadIdx.x];
    __syncthreads();
    const float cb2v = jb.cb2[0];
    const int wv = threadIdx.x >> 6, lane = threadIdx.x & 63;
    const int q = lane >> 4, mm = lane & 15;
    const int ebase = blockIdx.x * 64 + wv * 16;
    const int e = ebase + mm;
    const bool ev = e < nE;
    int ii = ev ? jb.dsti[e] : 0;
    int jj = ev ? jb.cj[e] : 0;
    float dx = jb.coors[(size_t)jj * 3]     - jb.coors[(size_t)ii * 3];
    float dy = jb.coors[(size_t)jj * 3 + 1] - jb.coors[(size_t)ii * 3 + 1];
    float dz = jb.coors[(size_t)jj * 3 + 2] - jb.coors[(size_t)ii * 3 + 2];
    float rd = dx * dx + dy * dy + dz * dz;
    const unsigned* Ar = jb.A16 + (size_t)ii * BUPAD;
    const unsigned* Br = jb.Bp + (size_t)jj * BUPAD;
    ffrag acc = {0.f, 0.f, 0.f, 0.f};
#pragma unroll 4
    for (int t = 0; t < 17; ++t) {
        int ks = t * 32 + q * 8;
        int ku = ks >> 1;
        uint4 au = *(const uint4*)(Ar + ku);
        uint4 bu = *(const uint4*)(Br + ku);
        float4 w0 = *(const float4*)(s_w + ks);
        float4 w1 = *(const float4*)(s_w + ks + 4);
        float g[8];
        g[0] = siluf(bf_lo(au.x) + bf_lo(bu.x) + rd * w0.x);
        g[1] = siluf(bf_hi(au.x) + bf_hi(bu.x) + rd * w0.y);
        g[2] = siluf(bf_lo(au.y) + bf_lo(bu.y) + rd * w0.z);
        g[3] = siluf(bf_hi(au.y) + bf_hi(bu.y) + rd * w0.w);
        g[4] = siluf(bf_lo(au.z) + bf_lo(bu.z) + rd * w1.x);
        g[5] = siluf(bf_hi(au.z) + bf_hi(bu.z) + rd * w1.y);
        g[6] = siluf(bf_lo(au.w) + bf_lo(bu.w) + rd * w1.z);
        g[7] = siluf(bf_hi(au.w) + bf_hi(bu.w) + rd * w1.w);
        bfrag ah;
        unsigned* ahp = (unsigned*)&ah;
        ahp[0] = pkbf(g[0], g[1]);
        ahp[1] = pkbf(g[2], g[3]);
        ahp[2] = pkbf(g[4], g[5]);
        ahp[3] = pkbf(g[6], g[7]);
        bfrag bh = *(const bfrag*)(jb.Wfh + (size_t)(t * 64 + lane) * 8);
        bfrag bl = *(const bfrag*)(jb.Wfl + (size_t)(t * 64 + lane) * 8);
        acc = __builtin_amdgcn_mfma_f32_16x16x32_bf16(ah, bh, acc, 0, 0, 0);
        acc = __builtin_amdgcn_mfma_f32_16x16x32_bf16(ah, bl, acc, 0, 0, 0);
    }
#pragma unroll
    for (int r = 0; r < 4; ++r) {
        int erow = q * 4 + r;
        float me = siluf(acc[r] + s_eb2[mm]);
        sM[wv][erow][mm] = me;
        int e2 = ebase + erow;
        if (e2 < nE) jb.me16[(size_t)e2 * 16 + mm] = f2bf(me);
    }
    // coordinate gate via MFMA: [16 edges] x [64 hid], k=16 channels (padded 32)
    bfrag ag;
    unsigned* agp = (unsigned*)&ag;
    if (q < 2) {
        float4 m0 = *(const float4*)&sM[wv][mm][q * 8];
        float4 m1 = *(const float4*)&sM[wv][mm][q * 8 + 4];
        agp[0] = pkbf(m0.x, m0.y);
        agp[1] = pkbf(m0.z, m0.w);
        agp[2] = pkbf(m1.x, m1.y);
        agp[3] = pkbf(m1.z, m1.w);
    } else {
        agp[0] = agp[1] = agp[2] = agp[3] = 0u;
    }
    float part[4] = {0.f, 0.f, 0.f, 0.f};
#pragma unroll
    for (int nt = 0; nt < 4; ++nt) {
        bfrag gh = *(const bfrag*)(jb.Wgh + (size_t)(nt * 64 + lane) * 8);
        bfrag gl = *(const bfrag*)(jb.Wgl + (size_t)(nt * 64 + lane) * 8);
        ffrag a2 = {0.f, 0.f, 0.f, 0.f};
        a2 = __builtin_amdgcn_mfma_f32_16x16x32_bf16(ag, gh, a2, 0, 0, 0);
        a2 = __builtin_amdgcn_mfma_f32_16x16x32_bf16(ag, gl, a2, 0, 0, 0);
        int n = nt * 16 + mm;
        float c1 = s_cb1[n], c2 = s_cw2[n];
#pragma unroll
        for (int r = 0; r < 4; ++r) part[r] += siluf(a2[r] + c1) * c2;
    }
#pragma unroll
    for (int r = 0; r < 4; ++r) {
        part[r] += __shfl_xor(part[r], 1);
        part[r] += __shfl_xor(part[r], 2);
        part[r] += __shfl_xor(part[r], 4);
        part[r] += __shfl_xor(part[r], 8);
    }
    int srcl = (lane >> 2) << 4;
    float cand0 = __shfl(part[0], srcl);
    float cand1 = __shfl(part[1], srcl);
    float cand2 = __shfl(part[2], srcl);
    float cand3 = __shfl(part[3], srcl);
    if (lane < 16) {
        int rr = lane & 3;
        float cwv = (rr == 0 ? cand0 : rr == 1 ? cand1 : rr == 2 ? cand2 : cand3) + cb2v;
        int e3 = ebase + lane;
        if (e3 < nE) {
            jb.cvec[(size_t)e3 * 3]     = cwv * dx;
            jb.cvec[(size_t)e3 * 3 + 1] = cwv * dy;
            jb.cvec[(size_t)e3 * 3 + 2] = cwv * dz;
        }
    }
}

// ---------------- EGNN CSR segment-sum: both graphs per launch ----------------
struct SJob {
    const int* rp; const unsigned short* me16; const float* cvec;
    const float* coors; float* coorsOut; float* macc;
};
__global__ __launch_bounds__(256) void k_seg2(SJob s0, SJob s1, int N) {
    const SJob jb = blockIdx.y ? s1 : s0;
    int node = blockIdx.x * 4 + (threadIdx.x >> 6);
    int lane = threadIdx.x & 63;
    if (node >= N) return;
    int s = jb.rp[node], en = jb.rp[node + 1];
    int x = lane >> 4, c = lane & 15;
    float msum = 0.f, csum = 0.f;
    for (int p = s + x; p < en; p += 4) {
        msum += bf2f(jb.me16[(size_t)p * 16 + c]);
        if (c < 3) csum += jb.cvec[(size_t)p * 3 + c];
    }
    msum += __shfl_xor(msum, 16); msum += __shfl_xor(msum, 32);
    csum += __shfl_xor(csum, 16); csum += __shfl_xor(csum, 32);
    if (lane < 16) jb.macc[(size_t)node * M_D + lane] = msum;
    if (lane < 3) jb.coorsOut[(size_t)node * 3 + lane] = jb.coors[(size_t)node * 3 + lane] + csum;
}

__global__ void k_dist(const float* __restrict__ Hb, const float* __restrict__ w2,
                       const float* __restrict__ b2, float* __restrict__ dist, int nE) {
    int e = blockIdx.x * 4 + (threadIdx.x >> 6);
    int lane = threadIdx.x & 63;
    if (e >= nE) return;
    const float* r = Hb + (size_t)e * H_D;
    float s = r[lane] * w2[lane] + r[lane + 64] * w2[lane + 64];
#pragma unroll
    for (int off = 32; off; off >>= 1) s += __shfl_xor(s, off);
    if (lane == 0) dist[e] = reluf(s + b2[0]);
}

// ---------------- host ----------------
extern "C" void kernel_launch(void* const* d_in, const int* in_sizes, int n_in,
                              void* d_out, int out_size, void* d_ws, size_t ws_size,
                              hipStream_t stream) {
    const float* x1_in = (const float*)d_in[0];
    const float* x2_in = (const float*)d_in[1];
    const float* pos1  = (const float*)d_in[2];
    const float* pos2  = (const float*)d_in[3];
    const int* ei_intra1 = (const int*)d_in[4];
    const int* ei_intra2 = (const int*)d_in[5];
    const int* ei_12 = (const int*)d_in[6];
    const int* ei_21 = (const int*)d_in[7];
    const int* ei_int = (const int*)d_in[8];
    const float* g0_w  = (const float*)d_in[9];
    const float* g0_as = (const float*)d_in[10];
    const float* g0_ad = (const float*)d_in[11];
    const float* g0_b  = (const float*)d_in[12];
    const float* g1_w  = (const float*)d_in[13];
    const float* g1_as = (const float*)d_in[14];
    const float* g1_ad = (const float*)d_in[15];
    const float* g1_b  = (const float*)d_in[16];
    const float* it_ws = (const float*)d_in[17];
    const float* it_wd = (const float*)d_in[18];
    const float* it_as = (const float*)d_in[19];
    const float* it_ad = (const float*)d_in[20];
    const float* it_b  = (const float*)d_in[21];
    const float* eg_e_w1 = (const float*)d_in[22];
    const float* eg_e_b1 = (const float*)d_in[23];
    const float* eg_e_w2 = (const float*)d_in[24];
    const float* eg_e_b2 = (const float*)d_in[25];
    const float* eg_c_w1 = (const float*)d_in[26];
    const float* eg_c_b1 = (const float*)d_in[27];
    const float* eg_c_w2 = (const float*)d_in[28];
    const float* eg_c_b2 = (const float*)d_in[29];
    const float* eg_n_w1 = (const float*)d_in[30];
    const float* eg_n_b1 = (const float*)d_in[31];
    const float* eg_n_w2 = (const float*)d_in[32];
    const float* eg_n_b2 = (const float*)d_in[33];
    const float* lin_w = (const float*)d_in[34];
    const float* lin_b = (const float*)d_in[35];
    const float* aux_w1 = (const float*)d_in[36];
    const float* aux_b1 = (const float*)d_in[37];
    const float* aux_w2 = (const float*)d_in[38];
    const float* aux_b2 = (const float*)d_in[39];
    float* dout = (float*)d_out;

    // ---- workspace layout ----
    float* wsf = (float*)d_ws;
    size_t off = 0;
    auto alloc = [&](size_t nfl) { float* p = wsf + off; off += (nfl + 255) & ~(size_t)255; return p; };
    float* x1a = alloc((size_t)NN * H_D);
    float* x2a = alloc((size_t)NN * H_D);
    float* x1b = alloc((size_t)NN * H_D);
    float* x2b = alloc((size_t)NN * H_D);
    float* esed = alloc(4 * NN);
    float* es1 = esed, *es2 = esed + NN, *ed1 = esed + 2 * NN, *ed2 = esed + 3 * NN;
    float* co1a = alloc(NN * 3);
    float* co1b = alloc(NN * 3);
    float* co2a = alloc(NN * 3);
    float* co2b = alloc(NN * 3);
    float* macc1 = alloc((size_t)NN * M_D);
    float* macc2 = alloc((size_t)NN * M_D);
    unsigned* A16a = (unsigned*)alloc((size_t)NN * BUPAD);
    unsigned* B16a = (unsigned*)alloc((size_t)NN * BUPAD);
    unsigned* A16b = (unsigned*)alloc((size_t)NN * BUPAD);
    unsigned* B16b = (unsigned*)alloc((size_t)NN * BUPAD);
    unsigned* h16a = (unsigned*)alloc((size_t)NN * 64);
    unsigned* h16b = (unsigned*)alloc((size_t)NN * 64);
    int* cnt4 = (int*)alloc(4 * NN);
    int* rp4 = (int*)alloc(4 * (NN + 1));
    int* cjI1 = (int*)alloc(EIA_D);
    int* cjI2 = (int*)alloc(EIA_D);
    int* cj12 = (int*)alloc(EIR_D);
    int* cj21 = (int*)alloc(EIR_D);
    int* dstI1 = (int*)alloc(EIA_D);
    int* dstI2 = (int*)alloc(EIA_D);
    int* iota = (int*)alloc(NN);
    unsigned short* Wt = (unsigned short*)alloc(1100000);
    unsigned short* Wf = (unsigned short*)alloc(45000);
    unsigned short* me16a = (unsigned short*)alloc((size_t)EIA_D * 8);
    unsigned short* me16b = (unsigned short*)alloc((size_t)EIA_D * 8);
    float* cveca = alloc((size_t)EIA_D * 3);
    float* cvecb = alloc((size_t)EIA_D * 3);
    float* nh1 = (float*)B16a;     // alias: B tables dead post-edge; pad cols re-zeroed each rebuild
    float* nh2 = (float*)B16b;
    float* Hb  = (float*)A16a;     // alias: table block dead at aux time

    const int N = NN, H = H_D;
    int gNW = (N + 3) / 4;
    int gEA = (EIA_D + 255) / 256;

    // ---- weight prep ----
    PrepArgs pa;
    unsigned woffs[29], wsz[29];
    unsigned wo = 0;
    int wi = 0;
    auto addw = [&](const float* src, int K, int Ncols) {
        int Kpad = (K + 31) & ~31;
        int Npad = (Ncols + 63) & ~63;
        pa.d[wi] = {src, wo, K, Ncols, Kpad, Npad};
        woffs[wi] = wo; wsz[wi] = (unsigned)(Npad * Kpad);
        wo += 2u * Npad * Kpad;
        ++wi;
    };
    addw(g0_w, FIN_D, H);                          // 0
    addw(g0_w + FIN_D * H, FIN_D, H);              // 1
    addw(g1_w, H, H);                              // 2
    addw(g1_w + H * H, H, H);                      // 3
    for (int p = 0; p < 4; ++p) addw(it_ws + (size_t)p * H * H, H, H);   // 4..7
    for (int p = 0; p < 4; ++p) addw(it_wd + (size_t)p * H * H, H, H);   // 8..11
    for (int p = 0; p < 4; ++p) {                  // 12..19
        const float* ew1 = eg_e_w1 + (size_t)p * EIN_D * EHID_D;
        addw(ew1, H, EHID_D);
        addw(ew1 + (size_t)H * EHID_D, H, EHID_D);
    }
    for (int p = 0; p < 4; ++p) addw(eg_n_w1 + (size_t)p * NIN_D * NHID_D, NIN_D, NHID_D);  // 20..23
    for (int p = 0; p < 4; ++p) addw(eg_n_w2 + (size_t)p * NHID_D * H, NHID_D, H);          // 24..27
    addw(aux_w1, 2 * H, H);                        // 28
    k_prep<<<dim3(29, 16), 256, 0, stream>>>(pa, Wt);
    k_prep_ew2<<<4, 256, 0, stream>>>(eg_e_w2, eg_c_w1, Wf);
    auto WH = [&](int i) { return (const unsigned short*)(Wt + woffs[i]); };
    auto WL = [&](int i) { return (const unsigned short*)(Wt + woffs[i] + wsz[i]); };

    // ---- CSRs + iota ----
    k_filli<<<(4 * N + 255) / 256, 256, 0, stream>>>(cnt4, 0, 4 * N);
    k_iota<<<(N + 255) / 256, 256, 0, stream>>>(iota, N);
    k_hist<<<gEA, 256, 0, stream>>>(ei_intra1 + EIA_D, EIA_D, cnt4);
    k_hist<<<gEA, 256, 0, stream>>>(ei_intra2 + EIA_D, EIA_D, cnt4 + N);
    k_hist<<<gEA, 256, 0, stream>>>(ei_12 + EIR_D, EIR_D, cnt4 + 2 * N);
    k_hist<<<gEA, 256, 0, stream>>>(ei_21 + EIR_D, EIR_D, cnt4 + 3 * N);
    k_scan4<<<4, 256, 0, stream>>>(cnt4, N, rp4);
    k_filli<<<(4 * N + 255) / 256, 256, 0, stream>>>(cnt4, 0, 4 * N);
    const int* rpI1 = rp4;
    const int* rpI2 = rp4 + (N + 1);
    const int* rp12 = rp4 + 2 * (N + 1);
    const int* rp21 = rp4 + 3 * (N + 1);
    k_scatter<<<gEA, 256, 0, stream>>>(ei_intra1, ei_intra1 + EIA_D, EIA_D, rpI1, cnt4, cjI1, dstI1);
    k_scatter<<<gEA, 256, 0, stream>>>(ei_intra2, ei_intra2 + EIA_D, EIA_D, rpI2, cnt4 + N, cjI2, dstI2);
    k_scatter<<<gEA, 256, 0, stream>>>(ei_12, ei_12 + EIR_D, EIR_D, rp12, cnt4 + 2 * N, cj12, nullptr);
    k_scatter<<<gEA, 256, 0, stream>>>(ei_21, ei_21 + EIR_D, EIR_D, rp21, cnt4 + 3 * N, cj21, nullptr);

    const int MB = (N + 127) / 128;   // 157
    MMJobs js{};

    // ---- GAT intra layers ----
    auto intraL = [&](auto kt_tag, const float* xa, const float* xb, int wa, int wb,
                      const float* as_a, const float* ad_a, const float* as_b, const float* ad_b,
                      const float* b_a, const float* b_b, float* oa, float* ob) {
        constexpr int KT = decltype(kt_tag)::value;
        js.j[0] = {xa, nullptr, nullptr, nullptr, WH(wa), WL(wa), nullptr, nullptr,
                   nullptr, (unsigned short*)h16a, as_a, ad_a, es1, ed1};
        js.j[1] = {xb, nullptr, nullptr, nullptr, WH(wb), WL(wb), nullptr, nullptr,
                   nullptr, (unsigned short*)h16b, as_b, ad_b, es2, ed2};
        k_mmf<0, false, 2, true, KT, false><<<dim3(MB, 1, 2), 256, 0, stream>>>(
            js, N, H, H, 2, KT * 32, 0);
        GatJob g0{rpI1, cjI1, 1, es1, ed1, h16a, b_a, oa};
        GatJob g1{rpI2, cjI2, 1, es2, ed2, h16b, b_b, ob};
        k_gat2<<<dim3(gNW, 2), 256, 0, stream>>>(g0, g1, N);
    };

    intraL(std::integral_constant<int, 2>{}, x1_in, x2_in, 0, 1,
           g0_as, g0_ad, g0_as + H, g0_ad + H, g0_b, g0_b + H, x1a, x2a);
    const float* cx1 = x1a;
    const float* cx2 = x2a;
    intraL(std::integral_constant<int, 4>{}, cx1, cx2, 2, 3,
           g1_as, g1_ad, g1_as + H, g1_ad + H, g1_b, g1_b + H, x1b, x2b);
    cx1 = x1b; cx2 = x2b;

    // ---- GAT cross layers: hs+hd in ONE z=4 launch ----
    {
        float* outs1[2] = {x1a, x1b};
        float* outs2[2] = {x2a, x2b};
        for (int l = 0; l < 2; ++l) {
            int p0 = l * 2 + 0, p1 = l * 2 + 1;
            float* o2 = outs2[l];
            float* o1 = outs1[l];
            js.j[0] = {cx1, nullptr, nullptr, nullptr, WH(4 + p0), WL(4 + p0), nullptr, nullptr,
                       nullptr, (unsigned short*)h16a, it_as + p0 * H, nullptr, es1, nullptr};
            js.j[1] = {cx2, nullptr, nullptr, nullptr, WH(4 + p1), WL(4 + p1), nullptr, nullptr,
                       nullptr, (unsigned short*)h16b, it_as + p1 * H, nullptr, es2, nullptr};
            js.j[2] = {cx2, nullptr, nullptr, nullptr, WH(8 + p0), WL(8 + p0), nullptr, nullptr,
                       nullptr, nullptr, it_ad + p0 * H, nullptr, ed1, nullptr};
            js.j[3] = {cx1, nullptr, nullptr, nullptr, WH(8 + p1), WL(8 + p1), nullptr, nullptr,
                       nullptr, nullptr, it_ad + p1 * H, nullptr, ed2, nullptr};
            k_mmf<0, false, 1, true, 4, false><<<dim3(MB, 1, 4), 256, 0, stream>>>(
                js, N, H, H, 2, 128, 0);
            GatJob g0{rp12, cj12, 0, es1, ed1, h16a, it_b + p0 * H, o2};
            GatJob g1{rp21, cj21, 0, es2, ed2, h16b, it_b + p1 * H, o1};
            k_gat2<<<dim3(gNW, 2), 256, 0, stream>>>(g0, g1, N);
            cx1 = o1; cx2 = o2;
        }
    }

    // ---- EGNN layers ----
    auto egnn_pair = [&](const float* f1, const float* f2, const float* c1, const float* c2,
                         int l, float* fo1, float* fo2, float* co1, float* co2) {
        int p0 = 2 * l, p1 = 2 * l + 1;
        js.j[0] = {f1, nullptr, nullptr, nullptr, WH(12 + 2 * p0), WL(12 + 2 * p0),
                   eg_e_b1 + p0 * EHID_D, nullptr, (float*)A16a, nullptr, nullptr, nullptr, nullptr, nullptr};
        js.j[1] = {f1, nullptr, nullptr, nullptr, WH(13 + 2 * p0), WL(13 + 2 * p0),
                   nullptr, nullptr, (float*)B16a, nullptr, nullptr, nullptr, nullptr, nullptr};
        js.j[2] = {f2, nullptr, nullptr, nullptr, WH(12 + 2 * p1), WL(12 + 2 * p1),
                   eg_e_b1 + p1 * EHID_D, nullptr, (float*)A16b, nullptr, nullptr, nullptr, nullptr, nullptr};
        js.j[3] = {f2, nullptr, nullptr, nullptr, WH(13 + 2 * p1), WL(13 + 2 * p1),
                   nullptr, nullptr, (float*)B16b, nullptr, nullptr, nullptr, nullptr, nullptr};
        k_mmf<0, true, 0, false, 4, false><<<dim3(MB, 1, 4), 256, 0, stream>>>(
            js, N, EHID_D, APAD, 9, 128, 0);
        const float* ew1a = eg_e_w1 + (size_t)p0 * EIN_D * EHID_D;
        const float* ew1b = eg_e_w1 + (size_t)p1 * EIN_D * EHID_D;
        EJob e0{dstI1, cjI1, A16a, B16a, c1, ew1a + (size_t)256 * EHID_D,
                Wf + (size_t)p0 * 8704, Wf + 4 * 8704 + (size_t)p0 * 8704,
                Wf + 69632 + (size_t)p0 * 4096, Wf + 69632 + (size_t)p0 * 4096 + 2048,
                eg_e_b2 + p0 * M_D, eg_c_b1 + p0 * 64,
                eg_c_w2 + p0 * 64, eg_c_b2 + p0, me16a, cveca};
        EJob e1{dstI2, cjI2, A16b, B16b, c2, ew1b + (size_t)256 * EHID_D,
                Wf + (size_t)p1 * 8704, Wf + 4 * 8704 + (size_t)p1 * 8704,
                Wf + 69632 + (size_t)p1 * 4096, Wf + 69632 + (size_t)p1 * 4096 + 2048,
                eg_e_b2 + p1 * M_D, eg_c_b1 + p1 * 64,
                eg_c_w2 + p1 * 64, eg_c_b2 + p1, me16b, cvecb};
        k_edge2<<<dim3((EIA_D + 63) / 64, 2), 256, 0, stream>>>(e0, e1, EIA_D);
        SJob s0{rpI1, me16a, cveca, c1, co1, macc1};
        SJob s1{rpI2, me16b, cvecb, c2, co2, macc2};
        k_seg2<<<dim3(gNW, 2), 256, 0, stream>>>(s0, s1, N);
        // nh: full-K resident gather-concat [feats(128) | macc(16)], Kact=144 (pad strip zeroed)
        js.j[0] = {f1, macc1, iota, iota, WH(20 + p0), WL(20 + p0),
                   eg_n_b1 + p0 * NHID_D, nullptr, nh1, nullptr, nullptr, nullptr, nullptr, nullptr};
        js.j[1] = {f2, macc2, iota, iota, WH(20 + p1), WL(20 + p1),
                   eg_n_b1 + p1 * NHID_D, nullptr, nh2, nullptr, nullptr, nullptr, nullptr, nullptr};
        k_mmf<2, false, 0, false, 5, true><<<dim3(MB, 1, 2), 256, 0, stream>>>(
            js, N, NHID_D, NHID_D, 4, NIN_D, M_D);
        // n_w2: K=256 -> multi-pass k_mm (16KB LDS, bn-parallel; KT=8 full-K regressed r13)
        js.j[0] = {nh1, nullptr, nullptr, nullptr, WH(24 + p0), WL(24 + p0),
                   eg_n_b2 + p0 * H, f1, fo1, nullptr, nullptr, nullptr, nullptr, nullptr};
        js.j[1] = {nh2, nullptr, nullptr, nullptr, WH(24 + p1), WL(24 + p1),
                   eg_n_b2 + p1 * H, f2, fo2, nullptr, nullptr, nullptr, nullptr, nullptr};
        k_mm<0, true, false><<<dim3(MB, 2, 2), 256, 0, stream>>>(js, N, H, NHID_D, NHID_D, H, 0);
    };
    egnn_pair(cx1, cx2, pos1, pos2, 0, x1a, x2a, co1a, co2a);
    cx1 = x1a; cx2 = x2a;
    egnn_pair(cx1, cx2, co1a, co2a, 1, x1b, x2b, co1b, co2b);
    cx1 = x1b; cx2 = x2b;

    // ---- heads ----
    k_nodescore<<<gNW, 256, 0, stream>>>(cx1, lin_w, lin_b, dout, N);
    k_nodescore<<<gNW, 256, 0, stream>>>(cx2, lin_w, lin_b, dout + N, N);
    js.j[0] = {cx1, cx2, ei_int, ei_int + EIT_D, WH(28), WL(28),
               aux_b1, nullptr, Hb, nullptr, nullptr, nullptr, nullptr, nullptr};
    k_mm<1, false, true><<<dim3((EIT_D + 127) / 128, 2, 1), 256, 0, stream>>>(
        js, EIT_D, H, 2 * H, 2 * H, H, H_D);
    k_dist<<<(EIT_D + 3) / 4, 256, 0, stream>>>(Hb, aux_w2, aux_b2, dout + 2 * N, EIT_D);
}

// Round 15
// 1442.197 us; speedup vs baseline: 1.0400x; 1.0110x over previous
//
#include <hip/hip_runtime.h>
#include <hip/hip_bf16.h>
#include <cstdint>
#include <cstddef>
#include <type_traits>

// ---- problem constants ----
#define NN     20000
#define FIN_D  64
#define H_D    128
#define M_D    16
#define EIA_D  256000
#define EIR_D  256000
#define EIT_D  100000
#define EIN_D  257
#define EHID_D 514
#define NIN_D  144
#define NHID_D 256
#define APAD   544          // padded EHID; 17 k-tiles of 32
#define BUPAD  272          // APAD/2 uints per bf16 row (A and B tables)

typedef short bfrag __attribute__((ext_vector_type(8)));   // 8 bf16 (4 VGPRs)
typedef float ffrag __attribute__((ext_vector_type(4)));   // 4 fp32 acc

__device__ __forceinline__ float siluf(float x) {
    return x * __builtin_amdgcn_rcpf(1.f + __expf(-x));
}
__device__ __forceinline__ float reluf(float x) { return x > 0.f ? x : 0.f; }
__device__ __forceinline__ unsigned short f2bf(float f) {  // RNE fp32->bf16
    unsigned u = __float_as_uint(f);
    return (unsigned short)((u + 0x7FFFu + ((u >> 16) & 1u)) >> 16);
}
__device__ __forceinline__ float bf2f(unsigned short h) { return __uint_as_float(((unsigned)h) << 16); }
__device__ __forceinline__ float bf_lo(unsigned u) { return __uint_as_float(u << 16); }
__device__ __forceinline__ float bf_hi(unsigned u) { return __uint_as_float(u & 0xFFFF0000u); }
__device__ __forceinline__ unsigned pkbf(float f0, float f1) {
    __hip_bfloat162 h = __float22bfloat162_rn(make_float2(f0, f1));
    return *(unsigned*)&h;
}

// ---------------- CSR build ----------------
__global__ void k_filli(int* p, int v, int n) {
    int i = blockIdx.x * 256 + threadIdx.x; if (i < n) p[i] = v;
}
__global__ void k_iota(int* p, int n) {
    int i = blockIdx.x * 256 + threadIdx.x; if (i < n) p[i] = i;
}
__global__ void k_hist(const int* __restrict__ si, int nE, int* __restrict__ cnt) {
    int e = blockIdx.x * 256 + threadIdx.x; if (e < nE) atomicAdd(&cnt[si[e]], 1);
}
__global__ void k_scan4(const int* __restrict__ cnt4, int n, int* __restrict__ rp4) {
    const int* cnt = cnt4 + (size_t)blockIdx.x * n;
    int* rp = rp4 + (size_t)blockIdx.x * (n + 1);
    __shared__ int tmp[256];
    __shared__ int carry;
    if (threadIdx.x == 0) { carry = 0; rp[0] = 0; }
    __syncthreads();
    for (int base = 0; base < n; base += 256) {
        int i = base + threadIdx.x;
        int v = (i < n) ? cnt[i] : 0;
        tmp[threadIdx.x] = v;
        __syncthreads();
        for (int off = 1; off < 256; off <<= 1) {
            int t = (threadIdx.x >= off) ? tmp[threadIdx.x - off] : 0;
            __syncthreads();
            tmp[threadIdx.x] += t;
            __syncthreads();
        }
        if (i < n) rp[i + 1] = carry + tmp[threadIdx.x];
        __syncthreads();
        if (threadIdx.x == 0) carry += tmp[255];
        __syncthreads();
    }
}
__global__ void k_scatter(const int* __restrict__ sj, const int* __restrict__ si, int nE,
                          const int* __restrict__ rp, int* __restrict__ cursor,
                          int* __restrict__ colj, int* __restrict__ dsti) {
    int e = blockIdx.x * 256 + threadIdx.x;
    if (e >= nE) return;
    int i = si[e];
    int p = rp[i] + atomicAdd(&cursor[i], 1);
    colj[p] = sj[e];
    if (dsti) dsti[p] = i;
}

// ---------------- weight prep: transpose + hi/lo bf16 split ----------------
struct PrepDesc { const float* src; unsigned dstOff; int K, N, Kpad, Npad; };
struct PrepArgs { PrepDesc d[29]; };
__global__ void k_prep(PrepArgs pa, unsigned short* __restrict__ Wt) {
    PrepDesc de = pa.d[blockIdx.x];
    int tot = de.Npad * de.Kpad;
    unsigned short* hi = Wt + de.dstOff;
    unsigned short* lo = hi + tot;
    for (int i = blockIdx.y * 256 + threadIdx.x; i < tot; i += gridDim.y * 256) {
        int n = i / de.Kpad, k = i - n * de.Kpad;
        float v = (n < de.N && k < de.K) ? de.src[(size_t)k * de.N + n] : 0.f;
        unsigned short h = f2bf(v);
        hi[i] = h;
        lo[i] = f2bf(v - bf2f(h));
    }
}

// ew2 [514][16] -> MFMA B-frag order (zero beyond k>=514); cw1 [16][64] -> gate B-frags
__global__ void k_prep_ew2(const float* __restrict__ eg_e_w2, const float* __restrict__ eg_c_w1,
                           unsigned short* __restrict__ Wf) {
    int pidx = blockIdx.x;
    const float* src = eg_e_w2 + (size_t)pidx * EHID_D * M_D;
    unsigned short* hi = Wf + (size_t)pidx * 8704;
    unsigned short* lo = Wf + 4 * 8704 + (size_t)pidx * 8704;
    for (int idx = threadIdx.x; idx < 8704; idx += 256) {
        int t = idx >> 9, rem = idx & 511;
        int lane = rem >> 3, j2 = rem & 7;
        int k = t * 32 + ((lane >> 4) << 3) + j2;
        int n = lane & 15;
        float v = (k < EHID_D) ? src[(size_t)k * 16 + n] : 0.f;
        unsigned short h = f2bf(v);
        hi[idx] = h;
        lo[idx] = f2bf(v - bf2f(h));
    }
    const float* cw1 = eg_c_w1 + (size_t)pidx * 16 * 64;
    unsigned short* ghi = Wf + 69632 + (size_t)pidx * 4096;
    unsigned short* glo = ghi + 2048;
    for (int idx = threadIdx.x; idx < 2048; idx += 256) {
        int nt = idx >> 9, rem = idx & 511;
        int lane = rem >> 3, j = rem & 7;
        int q = lane >> 4, mm = lane & 15;
        int k = q * 8 + j;
        float v = (k < 16) ? cw1[(size_t)k * 64 + nt * 16 + mm] : 0.f;
        unsigned short h = f2bf(v);
        ghi[idx] = h;
        glo[idx] = f2bf(v - bf2f(h));
    }
}

struct MMJob {
    const float* A; const float* A2;
    const int* gi0; const int* gi1;
    const unsigned short* Wh; const unsigned short* Wl;
    const float* bias; const float* res;
    float* C; unsigned short* C2;
    const float* da; const float* db;
    float* dota; float* dotb;
};
struct MMJobs { MMJob j[4]; };

// ---------------- full-K resident MFMA GEMM (K = KT*32 <= 128; 16-32KB LDS) ----------------
// A staged once in LDS (bf16), bn tiles looped internally. DOT: direct-store per-row dots.
// OBF pad cols Nc..ldc-1 zeroed (NaN-pad lesson r9). NOTE (r13/r14 lesson): for the tail
// GEMMs (nh/nw2/aux) block-parallelism beats A-traffic reduction — they stay on k_mm.
template<int ACT, bool OBF, int DOT, bool NOC, int KT>
__global__ __launch_bounds__(256) void k_mmf(MMJobs js, int M, int Nc, int ldc, int nbn) {
    constexpr int K = KT * 32;
    __shared__ __align__(16) unsigned short sAh[128 * K];
    const MMJob jb = js.j[blockIdx.z];
    const int tid = threadIdx.x;
    const int bm = blockIdx.x * 128;
    const int wv = tid >> 6, lane = tid & 63;
    const int q = lane >> 4, mm = lane & 15;
    const int sr = tid >> 1;
    const int sks = (tid & 1) * 16;
    const int gm_s = bm + sr;
    const int sgmt = sr >> 4, smm = sr & 15, qb = (tid & 1) * 2;
#pragma unroll
    for (int t = 0; t < KT; ++t) {
        float v[16];
        if (gm_s < M) {
            const float* src = jb.A + (size_t)gm_s * K + t * 32 + sks;
#pragma unroll
            for (int i = 0; i < 4; ++i) {
                float4 t4 = ((const float4*)src)[i];
                v[4 * i] = t4.x; v[4 * i + 1] = t4.y; v[4 * i + 2] = t4.z; v[4 * i + 3] = t4.w;
            }
        } else {
#pragma unroll
            for (int i = 0; i < 16; ++i) v[i] = 0.f;
        }
#pragma unroll
        for (int o = 0; o < 2; ++o) {
            unsigned hw[4];
#pragma unroll
            for (int p = 0; p < 4; ++p)
                hw[p] = pkbf(v[o * 8 + 2 * p], v[o * 8 + 2 * p + 1]);
            int off16 = ((sgmt * KT + t) * 4 + qb + o) * 16 + smm;
            ((uint4*)sAh)[off16] = make_uint4(hw[0], hw[1], hw[2], hw[3]);
        }
    }
    __syncthreads();
    float dra[2][4] = {}, drb[2][4] = {};
    for (int b = 0; b < nbn; ++b) {
        const int bn = b * 64;
        ffrag acc[2][4];
#pragma unroll
        for (int mt = 0; mt < 2; ++mt)
#pragma unroll
            for (int nt = 0; nt < 4; ++nt)
#pragma unroll
                for (int r = 0; r < 4; ++r) acc[mt][nt][r] = 0.f;
#pragma unroll
        for (int t = 0; t < KT; ++t) {
            bfrag bh[4], bl[4];
#pragma unroll
            for (int nt = 0; nt < 4; ++nt) {
                size_t woff = (size_t)(bn + nt * 16 + mm) * K + t * 32 + q * 8;
                bh[nt] = *(const bfrag*)(jb.Wh + woff);
                bl[nt] = *(const bfrag*)(jb.Wl + woff);
            }
#pragma unroll
            for (int mt = 0; mt < 2; ++mt) {
                int off16 = (((wv * 2 + mt) * KT + t) * 4 + q) * 16 + mm;
                bfrag ah = ((const bfrag*)sAh)[off16];
#pragma unroll
                for (int nt = 0; nt < 4; ++nt) {
                    acc[mt][nt] = __builtin_amdgcn_mfma_f32_16x16x32_bf16(ah, bh[nt], acc[mt][nt], 0, 0, 0);
                    acc[mt][nt] = __builtin_amdgcn_mfma_f32_16x16x32_bf16(ah, bl[nt], acc[mt][nt], 0, 0, 0);
                }
            }
        }
        if (DOT >= 1) {
            float dav[4], dbv[4];
#pragma unroll
            for (int nt = 0; nt < 4; ++nt) {
                int gn = bn + nt * 16 + mm;
                dav[nt] = (gn < Nc) ? jb.da[gn] : 0.f;
                if (DOT == 2) dbv[nt] = (gn < Nc) ? jb.db[gn] : 0.f;
            }
#pragma unroll
            for (int mt = 0; mt < 2; ++mt)
#pragma unroll
                for (int r = 0; r < 4; ++r)
#pragma unroll
                    for (int nt = 0; nt < 4; ++nt) {
                        dra[mt][r] += acc[mt][nt][r] * dav[nt];
                        if (DOT == 2) drb[mt][r] += acc[mt][nt][r] * dbv[nt];
                    }
        }
        const bool doC2 = jb.C2 != nullptr;
        if (!NOC || doC2) {
#pragma unroll
            for (int mt = 0; mt < 2; ++mt) {
#pragma unroll
                for (int nt = 0; nt < 4; ++nt) {
                    int gn = bn + nt * 16 + mm;
                    bool inb = gn < Nc;
                    bool padz = OBF && !NOC && !inb && gn < ldc;
                    if (!inb && !padz) continue;
#pragma unroll
                    for (int r = 0; r < 4; ++r) {
                        int gm = bm + wv * 32 + mt * 16 + q * 4 + r;
                        if (gm >= M) continue;
                        if (padz) {
                            ((unsigned short*)jb.C)[(size_t)gm * ldc + gn] = 0;
                            continue;
                        }
                        float vv = acc[mt][nt][r];
                        if (jb.bias) vv += jb.bias[gn];
                        if (ACT == 1) vv = reluf(vv);
                        if (ACT == 2) vv = siluf(vv);
                        if (!NOC) {
                            if (OBF) ((unsigned short*)jb.C)[(size_t)gm * ldc + gn] = f2bf(vv);
                            else jb.C[(size_t)gm * ldc + gn] = vv;
                        }
                        if (doC2) jb.C2[(size_t)gm * ldc + gn] = f2bf(vv);
                    }
                }
            }
        }
    }
    if (DOT >= 1) {
#pragma unroll
        for (int mt = 0; mt < 2; ++mt)
#pragma unroll
            for (int r = 0; r < 4; ++r) {
                float sa = dra[mt][r];
                sa += __shfl_xor(sa, 1); sa += __shfl_xor(sa, 2);
                sa += __shfl_xor(sa, 4); sa += __shfl_xor(sa, 8);
                float sb = 0.f;
                if (DOT == 2) {
                    sb = drb[mt][r];
                    sb += __shfl_xor(sb, 1); sb += __shfl_xor(sb, 2);
                    sb += __shfl_xor(sb, 4); sb += __shfl_xor(sb, 8);
                }
                int gm = bm + wv * 32 + mt * 16 + q * 4 + r;
                if (mm == 0 && gm < M) {
                    jb.dota[gm] = sa;
                    if (DOT == 2) jb.dotb[gm] = sb;
                }
            }
    }
}

// ---------------- general MFMA GEMM (AMODE=2 hi/lo; bn-parallel; nh/nw2/aux) ----------------
template<int ACT, bool RES, bool GATHER>
__global__ __launch_bounds__(256) void k_mm(MMJobs js, int M, int Nc, int K, int Kpad, int ldc, int s2) {
    __shared__ __align__(16) unsigned short sAh[128 * 32];
    __shared__ __align__(16) unsigned short sAl[128 * 32];
    const MMJob jb = js.j[blockIdx.z];
    const int tid = threadIdx.x;
    const int bm = blockIdx.x * 128, bn = blockIdx.y * 64;
    const int wv = tid >> 6, lane = tid & 63;
    ffrag acc[2][4];
#pragma unroll
    for (int mt = 0; mt < 2; ++mt)
#pragma unroll
        for (int nt = 0; nt < 4; ++nt)
#pragma unroll
            for (int r = 0; r < 4; ++r) acc[mt][nt][r] = 0.f;
    const int sr = tid >> 1;
    const int sks = (tid & 1) * 16;
    const int gm_s = bm + sr;
    const int sgmt = sr >> 4, smm = sr & 15, qb = (tid & 1) * 2;
    int gidx0 = 0, gidx1 = 0;
    if (GATHER && gm_s < M) { gidx0 = jb.gi0[gm_s]; gidx1 = jb.gi1[gm_s]; }
    const int q = lane >> 4, mm = lane & 15;

    for (int k0 = 0; k0 < Kpad; k0 += 32) {
        float v[16];
        bool valid = (gm_s < M) && (k0 + sks < K);
        if (valid) {
            const float* src;
            int kk = k0 + sks;
            if (GATHER) src = (kk < 128) ? (jb.A + (size_t)gidx0 * 128 + kk)
                                         : (jb.A2 + (size_t)gidx1 * s2 + (kk - 128));
            else src = jb.A + (size_t)gm_s * K + kk;
#pragma unroll
            for (int i = 0; i < 4; ++i) {
                float4 t4 = ((const float4*)src)[i];
                v[4 * i] = t4.x; v[4 * i + 1] = t4.y; v[4 * i + 2] = t4.z; v[4 * i + 3] = t4.w;
            }
        } else {
#pragma unroll
            for (int i = 0; i < 16; ++i) v[i] = 0.f;
        }
#pragma unroll
        for (int o = 0; o < 2; ++o) {
            unsigned hw[4], lw[4];
#pragma unroll
            for (int p = 0; p < 4; ++p) {
                float f0 = v[o * 8 + 2 * p], f1 = v[o * 8 + 2 * p + 1];
                unsigned short h0 = f2bf(f0), h1 = f2bf(f1);
                unsigned short l0 = f2bf(f0 - bf2f(h0)), l1 = f2bf(f1 - bf2f(h1));
                hw[p] = (unsigned)h0 | ((unsigned)h1 << 16);
                lw[p] = (unsigned)l0 | ((unsigned)l1 << 16);
            }
            int off16 = (sgmt * 4 + qb + o) * 16 + smm;
            ((uint4*)sAh)[off16] = make_uint4(hw[0], hw[1], hw[2], hw[3]);
            ((uint4*)sAl)[off16] = make_uint4(lw[0], lw[1], lw[2], lw[3]);
        }
        __syncthreads();
        bfrag bh[4], bl[4];
#pragma unroll
        for (int nt = 0; nt < 4; ++nt) {
            size_t woff = (size_t)(bn + nt * 16 + mm) * Kpad + k0 + q * 8;
            bh[nt] = *(const bfrag*)(jb.Wh + woff);
            bl[nt] = *(const bfrag*)(jb.Wl + woff);
        }
#pragma unroll
        for (int mt = 0; mt < 2; ++mt) {
            int off16 = ((wv * 2 + mt) * 4 + q) * 16 + mm;
            bfrag ah = ((const bfrag*)sAh)[off16];
            bfrag al = ((const bfrag*)sAl)[off16];
#pragma unroll
            for (int nt = 0; nt < 4; ++nt) {
                acc[mt][nt] = __builtin_amdgcn_mfma_f32_16x16x32_bf16(ah, bh[nt], acc[mt][nt], 0, 0, 0);
                acc[mt][nt] = __builtin_amdgcn_mfma_f32_16x16x32_bf16(ah, bl[nt], acc[mt][nt], 0, 0, 0);
                acc[mt][nt] = __builtin_amdgcn_mfma_f32_16x16x32_bf16(al, bh[nt], acc[mt][nt], 0, 0, 0);
            }
        }
        __syncthreads();
    }
#pragma unroll
    for (int mt = 0; mt < 2; ++mt) {
#pragma unroll
        for (int nt = 0; nt < 4; ++nt) {
            int gn = bn + nt * 16 + mm;
            if (gn >= Nc) continue;
#pragma unroll
            for (int r = 0; r < 4; ++r) {
                int gm = bm + wv * 32 + mt * 16 + q * 4 + r;
                if (gm >= M) continue;
                float vv = acc[mt][nt][r];
                if (jb.bias) vv += jb.bias[gn];
                if (ACT == 1) vv = reluf(vv);
                if (ACT == 2) vv = siluf(vv);
                if (RES) vv += jb.res[(size_t)gm * Nc + gn];
                jb.C[(size_t)gm * ldc + gn] = vv;
            }
        }
    }
}

__global__ void k_nodescore(const float* __restrict__ x, const float* __restrict__ wv,
                            const float* __restrict__ b, float* __restrict__ o, int n) {
    int w = blockIdx.x * 4 + (threadIdx.x >> 6);
    int lane = threadIdx.x & 63;
    if (w >= n) return;
    const float* r = x + (size_t)w * H_D;
    float s = r[lane] * wv[lane] + r[lane + 64] * wv[lane + 64];
#pragma unroll
    for (int off = 32; off; off >>= 1) s += __shfl_xor(s, off);
    if (lane == 0) o[w] = s + b[0];
}

// ---------------- fused GAT softmax-aggregate: both graphs per launch, 4-edge unroll --------
struct GatJob {
    const int* rp; const int* cj; int hasSelf;
    const float* es; const float* ed;
    const unsigned* h16; const float* bias; float* out;
};
__global__ __launch_bounds__(256) void k_gat2(GatJob j0, GatJob j1, int N) {
    const GatJob jb = blockIdx.y ? j1 : j0;
    int node = blockIdx.x * 4 + (threadIdx.x >> 6);
    int lane = threadIdx.x & 63;
    if (node >= N) return;
    int start = jb.rp[node], end = jb.rp[node + 1];
    float edi = jb.ed[node];
    float den = 0.f, a0 = 0.f, a1 = 0.f;
    int p = start;
    for (; p + 4 <= end; p += 4) {
        int j[4]; float e[4]; unsigned u[4];
#pragma unroll
        for (int x = 0; x < 4; ++x) j[x] = jb.cj[p + x];
#pragma unroll
        for (int x = 0; x < 4; ++x) { e[x] = jb.es[j[x]]; u[x] = jb.h16[(size_t)j[x] * 64 + lane]; }
#pragma unroll
        for (int x = 0; x < 4; ++x) {
            float v = e[x] + edi;
            v = v < 0.f ? 0.2f * v : v;
            float ex = __expf(v);
            den += ex;
            a0 += ex * bf_lo(u[x]);
            a1 += ex * bf_hi(u[x]);
        }
    }
    for (; p < end; ++p) {
        int j = jb.cj[p];
        float v = jb.es[j] + edi;
        v = v < 0.f ? 0.2f * v : v;
        float ex = __expf(v);
        den += ex;
        unsigned u = jb.h16[(size_t)j * 64 + lane];
        a0 += ex * bf_lo(u);
        a1 += ex * bf_hi(u);
    }
    if (jb.hasSelf) {
        float v = jb.es[node] + edi;
        v = v < 0.f ? 0.2f * v : v;
        float ex = __expf(v);
        den += ex;
        unsigned u = jb.h16[(size_t)node * 64 + lane];
        a0 += ex * bf_lo(u);
        a1 += ex * bf_hi(u);
    }
    float inv = 1.f / (den + 1e-16f);
    float2 o;
    o.x = reluf(a0 * inv + jb.bias[2 * lane]);
    o.y = reluf(a1 * inv + jb.bias[2 * lane + 1]);
    ((float2*)(jb.out + (size_t)node * H_D))[lane] = o;
}

// ---------------- EGNN edge kernel: both graphs per launch; MFMA gate ----------------
struct EJob {
    const int* dsti; const int* cj;
    const unsigned* A16; const unsigned* Bp; const float* coors;
    const float* w_rd;
    const unsigned short* Wfh; const unsigned short* Wfl;
    const unsigned short* Wgh; const unsigned short* Wgl;
    const float* eb2; const float* cb1;
    const float* cw2; const float* cb2;
    unsigned short* me16; float* cvec;
};
__global__ __launch_bounds__(256) void k_edge2(EJob e0, EJob e1, int nE) {
    const EJob jb = blockIdx.y ? e1 : e0;
    __shared__ __align__(16) float s_w[APAD];
    __shared__ float s_cb1[64], s_cw2[64], s_eb2[16];
    __shared__ __align__(16) float sM[4][16][20];
    for (int i = threadIdx.x; i < APAD; i += 256)
        s_w[i] = (i < EHID_D) ? jb.w_rd[i] : 0.f;
    if (threadIdx.x < 64) { s_cb1[threadIdx.x] = jb.cb1[threadIdx.x]; s_cw2[threadIdx.x] = jb.cw2[threadIdx.x]; }
    if (threadIdx.x < 16) s_eb2[threadIdx.x] = jb.eb2[threadIdx.x];
    __syncthreads();
    const float cb2v = jb.cb2[0];
    const int wv = threadIdx.x >> 6, lane = threadIdx.x & 63;
    const int q = lane >> 4, mm = lane & 15;
    const int ebase = blockIdx.x * 64 + wv * 16;
    const int e = ebase + mm;
    const bool ev = e < nE;
    int ii = ev ? jb.dsti[e] : 0;
    int jj = ev ? jb.cj[e] : 0;
    float dx = jb.coors[(size_t)jj * 3]     - jb.coors[(size_t)ii * 3];
    float dy = jb.coors[(size_t)jj * 3 + 1] - jb.coors[(size_t)ii * 3 + 1];
    float dz = jb.coors[(size_t)jj * 3 + 2] - jb.coors[(size_t)ii * 3 + 2];
    float rd = dx * dx + dy * dy + dz * dz;
    const unsigned* Ar = jb.A16 + (size_t)ii * BUPAD;
    const unsigned* Br = jb.Bp + (size_t)jj * BUPAD;
    ffrag acc = {0.f, 0.f, 0.f, 0.f};
#pragma unroll 4
    for (int t = 0; t < 17; ++t) {
        int ks = t * 32 + q * 8;
        int ku = ks >> 1;
        uint4 au = *(const uint4*)(Ar + ku);
        uint4 bu = *(const uint4*)(Br + ku);
        float4 w0 = *(const float4*)(s_w + ks);
        float4 w1 = *(const float4*)(s_w + ks + 4);
        float g[8];
        g[0] = siluf(bf_lo(au.x) + bf_lo(bu.x) + rd * w0.x);
        g[1] = siluf(bf_hi(au.x) + bf_hi(bu.x) + rd * w0.y);
        g[2] = siluf(bf_lo(au.y) + bf_lo(bu.y) + rd * w0.z);
        g[3] = siluf(bf_hi(au.y) + bf_hi(bu.y) + rd * w0.w);
        g[4] = siluf(bf_lo(au.z) + bf_lo(bu.z) + rd * w1.x);
        g[5] = siluf(bf_hi(au.z) + bf_hi(bu.z) + rd * w1.y);
        g[6] = siluf(bf_lo(au.w) + bf_lo(bu.w) + rd * w1.z);
        g[7] = siluf(bf_hi(au.w) + bf_hi(bu.w) + rd * w1.w);
        bfrag ah;
        unsigned* ahp = (unsigned*)&ah;
        ahp[0] = pkbf(g[0], g[1]);
        ahp[1] = pkbf(g[2], g[3]);
        ahp[2] = pkbf(g[4], g[5]);
        ahp[3] = pkbf(g[6], g[7]);
        bfrag bh = *(const bfrag*)(jb.Wfh + (size_t)(t * 64 + lane) * 8);
        bfrag bl = *(const bfrag*)(jb.Wfl + (size_t)(t * 64 + lane) * 8);
        acc = __builtin_amdgcn_mfma_f32_16x16x32_bf16(ah, bh, acc, 0, 0, 0);
        acc = __builtin_amdgcn_mfma_f32_16x16x32_bf16(ah, bl, acc, 0, 0, 0);
    }
#pragma unroll
    for (int r = 0; r < 4; ++r) {
        int erow = q * 4 + r;
        float me = siluf(acc[r] + s_eb2[mm]);
        sM[wv][erow][mm] = me;
        int e2 = ebase + erow;
        if (e2 < nE) jb.me16[(size_t)e2 * 16 + mm] = f2bf(me);
    }
    // coordinate gate via MFMA: [16 edges] x [64 hid], k=16 channels (padded 32)
    bfrag ag;
    unsigned* agp = (unsigned*)&ag;
    if (q < 2) {
        float4 m0 = *(const float4*)&sM[wv][mm][q * 8];
        float4 m1 = *(const float4*)&sM[wv][mm][q * 8 + 4];
        agp[0] = pkbf(m0.x, m0.y);
        agp[1] = pkbf(m0.z, m0.w);
        agp[2] = pkbf(m1.x, m1.y);
        agp[3] = pkbf(m1.z, m1.w);
    } else {
        agp[0] = agp[1] = agp[2] = agp[3] = 0u;
    }
    float part[4] = {0.f, 0.f, 0.f, 0.f};
#pragma unroll
    for (int nt = 0; nt < 4; ++nt) {
        bfrag gh = *(const bfrag*)(jb.Wgh + (size_t)(nt * 64 + lane) * 8);
        bfrag gl = *(const bfrag*)(jb.Wgl + (size_t)(nt * 64 + lane) * 8);
        ffrag a2 = {0.f, 0.f, 0.f, 0.f};
        a2 = __builtin_amdgcn_mfma_f32_16x16x32_bf16(ag, gh, a2, 0, 0, 0);
        a2 = __builtin_amdgcn_mfma_f32_16x16x32_bf16(ag, gl, a2, 0, 0, 0);
        int n = nt * 16 + mm;
        float c1 = s_cb1[n], c2 = s_cw2[n];
#pragma unroll
        for (int r = 0; r < 4; ++r) part[r] += siluf(a2[r] + c1) * c2;
    }
#pragma unroll
    for (int r = 0; r < 4; ++r) {
        part[r] += __shfl_xor(part[r], 1);
        part[r] += __shfl_xor(part[r], 2);
        part[r] += __shfl_xor(part[r], 4);
        part[r] += __shfl_xor(part[r], 8);
    }
    int srcl = (lane >> 2) << 4;
    float cand0 = __shfl(part[0], srcl);
    float cand1 = __shfl(part[1], srcl);
    float cand2 = __shfl(part[2], srcl);
    float cand3 = __shfl(part[3], srcl);
    if (lane < 16) {
        int rr = lane & 3;
        float cwv = (rr == 0 ? cand0 : rr == 1 ? cand1 : rr == 2 ? cand2 : cand3) + cb2v;
        int e3 = ebase + lane;
        if (e3 < nE) {
            jb.cvec[(size_t)e3 * 3]     = cwv * dx;
            jb.cvec[(size_t)e3 * 3 + 1] = cwv * dy;
            jb.cvec[(size_t)e3 * 3 + 2] = cwv * dz;
        }
    }
}

// ---------------- EGNN CSR segment-sum: both graphs per launch ----------------
struct SJob {
    const int* rp; const unsigned short* me16; const float* cvec;
    const float* coors; float* coorsOut; float* macc;
};
__global__ __launch_bounds__(256) void k_seg2(SJob s0, SJob s1, int N) {
    const SJob jb = blockIdx.y ? s1 : s0;
    int node = blockIdx.x * 4 + (threadIdx.x >> 6);
    int lane = threadIdx.x & 63;
    if (node >= N) return;
    int s = jb.rp[node], en = jb.rp[node + 1];
    int x = lane >> 4, c = lane & 15;
    float msum = 0.f, csum = 0.f;
    for (int p = s + x; p < en; p += 4) {
        msum += bf2f(jb.me16[(size_t)p * 16 + c]);
        if (c < 3) csum += jb.cvec[(size_t)p * 3 + c];
    }
    msum += __shfl_xor(msum, 16); msum += __shfl_xor(msum, 32);
    csum += __shfl_xor(csum, 16); csum += __shfl_xor(csum, 32);
    if (lane < 16) jb.macc[(size_t)node * M_D + lane] = msum;
    if (lane < 3) jb.coorsOut[(size_t)node * 3 + lane] = jb.coors[(size_t)node * 3 + lane] + csum;
}

__global__ void k_dist(const float* __restrict__ Hb, const float* __restrict__ w2,
                       const float* __restrict__ b2, float* __restrict__ dist, int nE) {
    int e = blockIdx.x * 4 + (threadIdx.x >> 6);
    int lane = threadIdx.x & 63;
    if (e >= nE) return;
    const float* r = Hb + (size_t)e * H_D;
    float s = r[lane] * w2[lane] + r[lane + 64] * w2[lane + 64];
#pragma unroll
    for (int off = 32; off; off >>= 1) s += __shfl_xor(s, off);
    if (lane == 0) dist[e] = reluf(s + b2[0]);
}

// ---------------- host ----------------
extern "C" void kernel_launch(void* const* d_in, const int* in_sizes, int n_in,
                              void* d_out, int out_size, void* d_ws, size_t ws_size,
                              hipStream_t stream) {
    const float* x1_in = (const float*)d_in[0];
    const float* x2_in = (const float*)d_in[1];
    const float* pos1  = (const float*)d_in[2];
    const float* pos2  = (const float*)d_in[3];
    const int* ei_intra1 = (const int*)d_in[4];
    const int* ei_intra2 = (const int*)d_in[5];
    const int* ei_12 = (const int*)d_in[6];
    const int* ei_21 = (const int*)d_in[7];
    const int* ei_int = (const int*)d_in[8];
    const float* g0_w  = (const float*)d_in[9];
    const float* g0_as = (const float*)d_in[10];
    const float* g0_ad = (const float*)d_in[11];
    const float* g0_b  = (const float*)d_in[12];
    const float* g1_w  = (const float*)d_in[13];
    const float* g1_as = (const float*)d_in[14];
    const float* g1_ad = (const float*)d_in[15];
    const float* g1_b  = (const float*)d_in[16];
    const float* it_ws = (const float*)d_in[17];
    const float* it_wd = (const float*)d_in[18];
    const float* it_as = (const float*)d_in[19];
    const float* it_ad = (const float*)d_in[20];
    const float* it_b  = (const float*)d_in[21];
    const float* eg_e_w1 = (const float*)d_in[22];
    const float* eg_e_b1 = (const float*)d_in[23];
    const float* eg_e_w2 = (const float*)d_in[24];
    const float* eg_e_b2 = (const float*)d_in[25];
    const float* eg_c_w1 = (const float*)d_in[26];
    const float* eg_c_b1 = (const float*)d_in[27];
    const float* eg_c_w2 = (const float*)d_in[28];
    const float* eg_c_b2 = (const float*)d_in[29];
    const float* eg_n_w1 = (const float*)d_in[30];
    const float* eg_n_b1 = (const float*)d_in[31];
    const float* eg_n_w2 = (const float*)d_in[32];
    const float* eg_n_b2 = (const float*)d_in[33];
    const float* lin_w = (const float*)d_in[34];
    const float* lin_b = (const float*)d_in[35];
    const float* aux_w1 = (const float*)d_in[36];
    const float* aux_b1 = (const float*)d_in[37];
    const float* aux_w2 = (const float*)d_in[38];
    const float* aux_b2 = (const float*)d_in[39];
    float* dout = (float*)d_out;

    // ---- workspace layout ----
    float* wsf = (float*)d_ws;
    size_t off = 0;
    auto alloc = [&](size_t nfl) { float* p = wsf + off; off += (nfl + 255) & ~(size_t)255; return p; };
    float* x1a = alloc((size_t)NN * H_D);
    float* x2a = alloc((size_t)NN * H_D);
    float* x1b = alloc((size_t)NN * H_D);
    float* x2b = alloc((size_t)NN * H_D);
    float* esed = alloc(4 * NN);
    float* es1 = esed, *es2 = esed + NN, *ed1 = esed + 2 * NN, *ed2 = esed + 3 * NN;
    float* co1a = alloc(NN * 3);
    float* co1b = alloc(NN * 3);
    float* co2a = alloc(NN * 3);
    float* co2b = alloc(NN * 3);
    float* macc1 = alloc((size_t)NN * M_D);
    float* macc2 = alloc((size_t)NN * M_D);
    unsigned* A16a = (unsigned*)alloc((size_t)NN * BUPAD);
    unsigned* B16a = (unsigned*)alloc((size_t)NN * BUPAD);
    unsigned* A16b = (unsigned*)alloc((size_t)NN * BUPAD);
    unsigned* B16b = (unsigned*)alloc((size_t)NN * BUPAD);
    unsigned* h16a = (unsigned*)alloc((size_t)NN * 64);
    unsigned* h16b = (unsigned*)alloc((size_t)NN * 64);
    int* cnt4 = (int*)alloc(4 * NN);
    int* rp4 = (int*)alloc(4 * (NN + 1));
    int* cjI1 = (int*)alloc(EIA_D);
    int* cjI2 = (int*)alloc(EIA_D);
    int* cj12 = (int*)alloc(EIR_D);
    int* cj21 = (int*)alloc(EIR_D);
    int* dstI1 = (int*)alloc(EIA_D);
    int* dstI2 = (int*)alloc(EIA_D);
    int* iota = (int*)alloc(NN);
    unsigned short* Wt = (unsigned short*)alloc(1100000);
    unsigned short* Wf = (unsigned short*)alloc(45000);
    unsigned short* me16a = (unsigned short*)alloc((size_t)EIA_D * 8);
    unsigned short* me16b = (unsigned short*)alloc((size_t)EIA_D * 8);
    float* cveca = alloc((size_t)EIA_D * 3);
    float* cvecb = alloc((size_t)EIA_D * 3);
    float* nh1 = (float*)B16a;     // alias: B tables dead post-edge; pad cols re-zeroed each rebuild
    float* nh2 = (float*)B16b;
    float* Hb  = (float*)A16a;     // alias: table block dead at aux time

    const int N = NN, H = H_D;
    int gNW = (N + 3) / 4;
    int gEA = (EIA_D + 255) / 256;

    // ---- weight prep ----
    PrepArgs pa;
    unsigned woffs[29], wsz[29];
    unsigned wo = 0;
    int wi = 0;
    auto addw = [&](const float* src, int K, int Ncols) {
        int Kpad = (K + 31) & ~31;
        int Npad = (Ncols + 63) & ~63;
        pa.d[wi] = {src, wo, K, Ncols, Kpad, Npad};
        woffs[wi] = wo; wsz[wi] = (unsigned)(Npad * Kpad);
        wo += 2u * Npad * Kpad;
        ++wi;
    };
    addw(g0_w, FIN_D, H);                          // 0
    addw(g0_w + FIN_D * H, FIN_D, H);              // 1
    addw(g1_w, H, H);                              // 2
    addw(g1_w + H * H, H, H);                      // 3
    for (int p = 0; p < 4; ++p) addw(it_ws + (size_t)p * H * H, H, H);   // 4..7
    for (int p = 0; p < 4; ++p) addw(it_wd + (size_t)p * H * H, H, H);   // 8..11
    for (int p = 0; p < 4; ++p) {                  // 12..19
        const float* ew1 = eg_e_w1 + (size_t)p * EIN_D * EHID_D;
        addw(ew1, H, EHID_D);
        addw(ew1 + (size_t)H * EHID_D, H, EHID_D);
    }
    for (int p = 0; p < 4; ++p) addw(eg_n_w1 + (size_t)p * NIN_D * NHID_D, NIN_D, NHID_D);  // 20..23
    for (int p = 0; p < 4; ++p) addw(eg_n_w2 + (size_t)p * NHID_D * H, NHID_D, H);          // 24..27
    addw(aux_w1, 2 * H, H);                        // 28
    k_prep<<<dim3(29, 16), 256, 0, stream>>>(pa, Wt);
    k_prep_ew2<<<4, 256, 0, stream>>>(eg_e_w2, eg_c_w1, Wf);
    auto WH = [&](int i) { return (const unsigned short*)(Wt + woffs[i]); };
    auto WL = [&](int i) { return (const unsigned short*)(Wt + woffs[i] + wsz[i]); };

    // ---- CSRs + iota ----
    k_filli<<<(4 * N + 255) / 256, 256, 0, stream>>>(cnt4, 0, 4 * N);
    k_iota<<<(N + 255) / 256, 256, 0, stream>>>(iota, N);
    k_hist<<<gEA, 256, 0, stream>>>(ei_intra1 + EIA_D, EIA_D, cnt4);
    k_hist<<<gEA, 256, 0, stream>>>(ei_intra2 + EIA_D, EIA_D, cnt4 + N);
    k_hist<<<gEA, 256, 0, stream>>>(ei_12 + EIR_D, EIR_D, cnt4 + 2 * N);
    k_hist<<<gEA, 256, 0, stream>>>(ei_21 + EIR_D, EIR_D, cnt4 + 3 * N);
    k_scan4<<<4, 256, 0, stream>>>(cnt4, N, rp4);
    k_filli<<<(4 * N + 255) / 256, 256, 0, stream>>>(cnt4, 0, 4 * N);
    const int* rpI1 = rp4;
    const int* rpI2 = rp4 + (N + 1);
    const int* rp12 = rp4 + 2 * (N + 1);
    const int* rp21 = rp4 + 3 * (N + 1);
    k_scatter<<<gEA, 256, 0, stream>>>(ei_intra1, ei_intra1 + EIA_D, EIA_D, rpI1, cnt4, cjI1, dstI1);
    k_scatter<<<gEA, 256, 0, stream>>>(ei_intra2, ei_intra2 + EIA_D, EIA_D, rpI2, cnt4 + N, cjI2, dstI2);
    k_scatter<<<gEA, 256, 0, stream>>>(ei_12, ei_12 + EIR_D, EIR_D, rp12, cnt4 + 2 * N, cj12, nullptr);
    k_scatter<<<gEA, 256, 0, stream>>>(ei_21, ei_21 + EIR_D, EIR_D, rp21, cnt4 + 3 * N, cj21, nullptr);

    const int MB = (N + 127) / 128;   // 157
    MMJobs js{};

    // ---- GAT intra layers ----
    auto intraL = [&](auto kt_tag, const float* xa, const float* xb, int wa, int wb,
                      const float* as_a, const float* ad_a, const float* as_b, const float* ad_b,
                      const float* b_a, const float* b_b, float* oa, float* ob) {
        constexpr int KT = decltype(kt_tag)::value;
        js.j[0] = {xa, nullptr, nullptr, nullptr, WH(wa), WL(wa), nullptr, nullptr,
                   nullptr, (unsigned short*)h16a, as_a, ad_a, es1, ed1};
        js.j[1] = {xb, nullptr, nullptr, nullptr, WH(wb), WL(wb), nullptr, nullptr,
                   nullptr, (unsigned short*)h16b, as_b, ad_b, es2, ed2};
        k_mmf<0, false, 2, true, KT><<<dim3(MB, 1, 2), 256, 0, stream>>>(js, N, H, H, 2);
        GatJob g0{rpI1, cjI1, 1, es1, ed1, h16a, b_a, oa};
        GatJob g1{rpI2, cjI2, 1, es2, ed2, h16b, b_b, ob};
        k_gat2<<<dim3(gNW, 2), 256, 0, stream>>>(g0, g1, N);
    };

    intraL(std::integral_constant<int, 2>{}, x1_in, x2_in, 0, 1,
           g0_as, g0_ad, g0_as + H, g0_ad + H, g0_b, g0_b + H, x1a, x2a);
    const float* cx1 = x1a;
    const float* cx2 = x2a;
    intraL(std::integral_constant<int, 4>{}, cx1, cx2, 2, 3,
           g1_as, g1_ad, g1_as + H, g1_ad + H, g1_b, g1_b + H, x1b, x2b);
    cx1 = x1b; cx2 = x2b;

    // ---- GAT cross layers: hs+hd in ONE z=4 launch ----
    {
        float* outs1[2] = {x1a, x1b};
        float* outs2[2] = {x2a, x2b};
        for (int l = 0; l < 2; ++l) {
            int p0 = l * 2 + 0, p1 = l * 2 + 1;
            float* o2 = outs2[l];
            float* o1 = outs1[l];
            js.j[0] = {cx1, nullptr, nullptr, nullptr, WH(4 + p0), WL(4 + p0), nullptr, nullptr,
                       nullptr, (unsigned short*)h16a, it_as + p0 * H, nullptr, es1, nullptr};
            js.j[1] = {cx2, nullptr, nullptr, nullptr, WH(4 + p1), WL(4 + p1), nullptr, nullptr,
                       nullptr, (unsigned short*)h16b, it_as + p1 * H, nullptr, es2, nullptr};
            js.j[2] = {cx2, nullptr, nullptr, nullptr, WH(8 + p0), WL(8 + p0), nullptr, nullptr,
                       nullptr, nullptr, it_ad + p0 * H, nullptr, ed1, nullptr};
            js.j[3] = {cx1, nullptr, nullptr, nullptr, WH(8 + p1), WL(8 + p1), nullptr, nullptr,
                       nullptr, nullptr, it_ad + p1 * H, nullptr, ed2, nullptr};
            k_mmf<0, false, 1, true, 4><<<dim3(MB, 1, 4), 256, 0, stream>>>(js, N, H, H, 2);
            GatJob g0{rp12, cj12, 0, es1, ed1, h16a, it_b + p0 * H, o2};
            GatJob g1{rp21, cj21, 0, es2, ed2, h16b, it_b + p1 * H, o1};
            k_gat2<<<dim3(gNW, 2), 256, 0, stream>>>(g0, g1, N);
            cx1 = o1; cx2 = o2;
        }
    }

    // ---- EGNN layers ----
    auto egnn_pair = [&](const float* f1, const float* f2, const float* c1, const float* c2,
                         int l, float* fo1, float* fo2, float* co1, float* co2) {
        int p0 = 2 * l, p1 = 2 * l + 1;
        js.j[0] = {f1, nullptr, nullptr, nullptr, WH(12 + 2 * p0), WL(12 + 2 * p0),
                   eg_e_b1 + p0 * EHID_D, nullptr, (float*)A16a, nullptr, nullptr, nullptr, nullptr, nullptr};
        js.j[1] = {f1, nullptr, nullptr, nullptr, WH(13 + 2 * p0), WL(13 + 2 * p0),
                   nullptr, nullptr, (float*)B16a, nullptr, nullptr, nullptr, nullptr, nullptr};
        js.j[2] = {f2, nullptr, nullptr, nullptr, WH(12 + 2 * p1), WL(12 + 2 * p1),
                   eg_e_b1 + p1 * EHID_D, nullptr, (float*)A16b, nullptr, nullptr, nullptr, nullptr, nullptr};
        js.j[3] = {f2, nullptr, nullptr, nullptr, WH(13 + 2 * p1), WL(13 + 2 * p1),
                   nullptr, nullptr, (float*)B16b, nullptr, nullptr, nullptr, nullptr, nullptr};
        k_mmf<0, true, 0, false, 4><<<dim3(MB, 1, 4), 256, 0, stream>>>(js, N, EHID_D, APAD, 9);
        const float* ew1a = eg_e_w1 + (size_t)p0 * EIN_D * EHID_D;
        const float* ew1b = eg_e_w1 + (size_t)p1 * EIN_D * EHID_D;
        EJob e0{dstI1, cjI1, A16a, B16a, c1, ew1a + (size_t)256 * EHID_D,
                Wf + (size_t)p0 * 8704, Wf + 4 * 8704 + (size_t)p0 * 8704,
                Wf + 69632 + (size_t)p0 * 4096, Wf + 69632 + (size_t)p0 * 4096 + 2048,
                eg_e_b2 + p0 * M_D, eg_c_b1 + p0 * 64,
                eg_c_w2 + p0 * 64, eg_c_b2 + p0, me16a, cveca};
        EJob e1{dstI2, cjI2, A16b, B16b, c2, ew1b + (size_t)256 * EHID_D,
                Wf + (size_t)p1 * 8704, Wf + 4 * 8704 + (size_t)p1 * 8704,
                Wf + 69632 + (size_t)p1 * 4096, Wf + 69632 + (size_t)p1 * 4096 + 2048,
                eg_e_b2 + p1 * M_D, eg_c_b1 + p1 * 64,
                eg_c_w2 + p1 * 64, eg_c_b2 + p1, me16b, cvecb};
        k_edge2<<<dim3((EIA_D + 63) / 64, 2), 256, 0, stream>>>(e0, e1, EIA_D);
        SJob s0{rpI1, me16a, cveca, c1, co1, macc1};
        SJob s1{rpI2, me16b, cvecb, c2, co2, macc2};
        k_seg2<<<dim3(gNW, 2), 256, 0, stream>>>(s0, s1, N);
        // nh: bn-parallel k_mm gather-concat [feats|macc] (r12 best config)
        js.j[0] = {f1, macc1, iota, iota, WH(20 + p0), WL(20 + p0),
                   eg_n_b1 + p0 * NHID_D, nullptr, nh1, nullptr, nullptr, nullptr, nullptr, nullptr};
        js.j[1] = {f2, macc2, iota, iota, WH(20 + p1), WL(20 + p1),
                   eg_n_b1 + p1 * NHID_D, nullptr, nh2, nullptr, nullptr, nullptr, nullptr, nullptr};
        k_mm<2, false, true><<<dim3(MB, 4, 2), 256, 0, stream>>>(js, N, NHID_D, NIN_D, 160, NHID_D, M_D);
        // n_w2: bn-parallel k_mm (+residual)
        js.j[0] = {nh1, nullptr, nullptr, nullptr, WH(24 + p0), WL(24 + p0),
                   eg_n_b2 + p0 * H, f1, fo1, nullptr, nullptr, nullptr, nullptr, nullptr};
        js.j[1] = {nh2, nullptr, nullptr, nullptr, WH(24 + p1), WL(24 + p1),
                   eg_n_b2 + p1 * H, f2, fo2, nullptr, nullptr, nullptr, nullptr, nullptr};
        k_mm<0, true, false><<<dim3(MB, 2, 2), 256, 0, stream>>>(js, N, H, NHID_D, NHID_D, H, 0);
    };
    egnn_pair(cx1, cx2, pos1, pos2, 0, x1a, x2a, co1a, co2a);
    cx1 = x1a; cx2 = x2a;
    egnn_pair(cx1, cx2, co1a, co2a, 1, x1b, x2b, co1b, co2b);
    cx1 = x1b; cx2 = x2b;

    // ---- heads ----
    k_nodescore<<<gNW, 256, 0, stream>>>(cx1, lin_w, lin_b, dout, N);
    k_nodescore<<<gNW, 256, 0, stream>>>(cx2, lin_w, lin_b, dout + N, N);
    js.j[0] = {cx1, cx2, ei_int, ei_int + EIT_D, WH(28), WL(28),
               aux_b1, nullptr, Hb, nullptr, nullptr, nullptr, nullptr, nullptr};
    k_mm<1, false, true><<<dim3((EIT_D + 127) / 128, 2, 1), 256, 0, stream>>>(
        js, EIT_D, H, 2 * H, 2 * H, H, H_D);
    k_dist<<<(EIT_D + 3) / 4, 256, 0, stream>>>(Hb, aux_w2, aux_b2, dout + 2 * N, EIT_D);
}